// Round 6
// baseline (525.201 us; speedup 1.0000x reference)
//
#include <hip/hip_runtime.h>
#include <math.h>

constexpr float NEG_SLOPE = 0.2f;

__device__ __forceinline__ float lrelu(float x) { return x > 0.f ? x : NEG_SLOPE * x; }

__device__ __forceinline__ float readlane_f(float v, int l) {
    return __uint_as_float(__builtin_amdgcn_readlane(__float_as_uint(v), l));
}
__device__ __forceinline__ int readlane_i(int v, int l) {
    return __builtin_amdgcn_readlane(v, l);
}

#define MAC16(av, bv) \
    acc[0][0] += av.x*bv.x; acc[0][1] += av.x*bv.y; acc[0][2] += av.x*bv.z; acc[0][3] += av.x*bv.w; \
    acc[1][0] += av.y*bv.x; acc[1][1] += av.y*bv.y; acc[1][2] += av.y*bv.z; acc[1][3] += av.y*bv.w; \
    acc[2][0] += av.z*bv.x; acc[2][1] += av.z*bv.y; acc[2][2] += av.z*bv.z; acc[2][3] += av.z*bv.w; \
    acc[3][0] += av.w*bv.x; acc[3][1] += av.w*bv.y; acc[3][2] += av.w*bv.z; acc[3][3] += av.w*bv.w;

// ---------------- GEMM1: h1 = x @ W1 (64x64 tile, 4x4/thread) ----------------
// Output rows stride 80: [0..63]=h, [64..71]=alpha_src per head. alpha_dst -> adn[N,8].
__global__ __launch_bounds__(256) void gemm1_kernel(
    const float* __restrict__ X, const float* __restrict__ W,
    const float* __restrict__ a_s, const float* __restrict__ a_d,
    float* __restrict__ H, float* __restrict__ adn, int N)
{
    __shared__ float At[128 * 64];
    __shared__ float Bs[128 * 64];
    const int tid = threadIdx.x;
    const int r_base = blockIdx.x * 64;
    {
        const float4* W4 = (const float4*)W;
        float4* B4 = (float4*)Bs;
#pragma unroll
        for (int it = 0; it < 8; ++it) B4[tid + it * 256] = W4[tid + it * 256];
    }
    {
        const float4* X4 = (const float4*)X;
#pragma unroll
        for (int it = 0; it < 2; ++it) {
            int t = tid + it * 256;          // 512 tasks: 4x4 block transpose
            int rg = t & 15, cg = t >> 4;    // rg: row quad, cg: k quad (0..31)
            float4 rw[4];
#pragma unroll
            for (int j = 0; j < 4; ++j) {
                int r = r_base + rg * 4 + j;
                rw[j] = (r < N) ? X4[(size_t)r * 32 + cg] : make_float4(0.f, 0.f, 0.f, 0.f);
            }
            int rsw = 4 * (rg ^ (cg & 15));
            int k0 = cg * 4;
            *(float4*)&At[(k0    ) * 64 + rsw] = make_float4(rw[0].x, rw[1].x, rw[2].x, rw[3].x);
            *(float4*)&At[(k0 + 1) * 64 + rsw] = make_float4(rw[0].y, rw[1].y, rw[2].y, rw[3].y);
            *(float4*)&At[(k0 + 2) * 64 + rsw] = make_float4(rw[0].z, rw[1].z, rw[2].z, rw[3].z);
            *(float4*)&At[(k0 + 3) * 64 + rsw] = make_float4(rw[0].w, rw[1].w, rw[2].w, rw[3].w);
        }
    }
    __syncthreads();
    const int m  = tid & 15;
    const int ci = (tid >> 4) * 4;
    float acc[4][4] = {};
#pragma unroll 4
    for (int kq = 0; kq < 32; ++kq) {
        int aoff = kq * 256 + 4 * (m ^ (kq & 15));
        int boff = kq * 256 + ci;
        float4 a0 = *(const float4*)&At[aoff];
        float4 a1 = *(const float4*)&At[aoff + 64];
        float4 a2 = *(const float4*)&At[aoff + 128];
        float4 a3 = *(const float4*)&At[aoff + 192];
        float4 b0 = *(const float4*)&Bs[boff];
        float4 b1 = *(const float4*)&Bs[boff + 64];
        float4 b2 = *(const float4*)&Bs[boff + 128];
        float4 b3 = *(const float4*)&Bs[boff + 192];
        MAC16(a0, b0); MAC16(a1, b1); MAC16(a2, b2); MAC16(a3, b3);
    }
    float asv[4] = {a_s[ci], a_s[ci + 1], a_s[ci + 2], a_s[ci + 3]};
    float adv[4] = {a_d[ci], a_d[ci + 1], a_d[ci + 2], a_d[ci + 3]};
    int head = ci >> 3;
    bool owner = ((tid >> 4) & 1) == 0;
#pragma unroll
    for (int j = 0; j < 4; ++j) {
        int r = r_base + m * 4 + j;
        if (r < N) *(float4*)&H[(size_t)r * 80 + ci] =
            make_float4(acc[j][0], acc[j][1], acc[j][2], acc[j][3]);
        float ps = acc[j][0]*asv[0] + acc[j][1]*asv[1] + acc[j][2]*asv[2] + acc[j][3]*asv[3];
        float pd = acc[j][0]*adv[0] + acc[j][1]*adv[1] + acc[j][2]*adv[2] + acc[j][3]*adv[3];
        ps += __shfl_xor(ps, 16);
        pd += __shfl_xor(pd, 16);
        if (owner && r < N) { H[(size_t)r * 80 + 64 + head] = ps; adn[r * 8 + head] = pd; }
    }
}

// ---------------- GEMM2: z = h2 @ W2 (64x64 tile) ----------------
// X dense stride 64; output rows stride 80: [0..63]=z, [64]=alpha_src. alpha_dst -> adn[N].
__global__ __launch_bounds__(256) void gemm2_kernel(
    const float* __restrict__ X, const float* __restrict__ W,
    const float* __restrict__ a_s, const float* __restrict__ a_d,
    float* __restrict__ H, float* __restrict__ adn, int N)
{
    __shared__ float At[64 * 64];
    __shared__ float Bs[64 * 64];
    __shared__ float Ps[4][16][4], Pd[4][16][4];
    const int tid = threadIdx.x;
    const int r_base = blockIdx.x * 64;
    {
        const float4* W4 = (const float4*)W;
        float4* B4 = (float4*)Bs;
#pragma unroll
        for (int it = 0; it < 4; ++it) B4[tid + it * 256] = W4[tid + it * 256];
    }
    {
        const float4* X4 = (const float4*)X;
        int rg = tid & 15, cg = tid >> 4;    // cg 0..15
        float4 rw[4];
#pragma unroll
        for (int j = 0; j < 4; ++j) {
            int r = r_base + rg * 4 + j;
            rw[j] = (r < N) ? X4[(size_t)r * 16 + cg] : make_float4(0.f, 0.f, 0.f, 0.f);
        }
        int rsw = 4 * (rg ^ (cg & 15));
        int k0 = cg * 4;
        *(float4*)&At[(k0    ) * 64 + rsw] = make_float4(rw[0].x, rw[1].x, rw[2].x, rw[3].x);
        *(float4*)&At[(k0 + 1) * 64 + rsw] = make_float4(rw[0].y, rw[1].y, rw[2].y, rw[3].y);
        *(float4*)&At[(k0 + 2) * 64 + rsw] = make_float4(rw[0].z, rw[1].z, rw[2].z, rw[3].z);
        *(float4*)&At[(k0 + 3) * 64 + rsw] = make_float4(rw[0].w, rw[1].w, rw[2].w, rw[3].w);
    }
    __syncthreads();
    const int m  = tid & 15;
    const int ci = (tid >> 4) * 4;
    float acc[4][4] = {};
#pragma unroll 4
    for (int kq = 0; kq < 16; ++kq) {
        int aoff = kq * 256 + 4 * (m ^ (kq & 15));
        int boff = kq * 256 + ci;
        float4 a0 = *(const float4*)&At[aoff];
        float4 a1 = *(const float4*)&At[aoff + 64];
        float4 a2 = *(const float4*)&At[aoff + 128];
        float4 a3 = *(const float4*)&At[aoff + 192];
        float4 b0 = *(const float4*)&Bs[boff];
        float4 b1 = *(const float4*)&Bs[boff + 64];
        float4 b2 = *(const float4*)&Bs[boff + 128];
        float4 b3 = *(const float4*)&Bs[boff + 192];
        MAC16(a0, b0); MAC16(a1, b1); MAC16(a2, b2); MAC16(a3, b3);
    }
    float asv[4] = {a_s[ci], a_s[ci + 1], a_s[ci + 2], a_s[ci + 3]};
    float adv[4] = {a_d[ci], a_d[ci + 1], a_d[ci + 2], a_d[ci + 3]};
    int w = tid >> 6;
    float ps[4], pd[4];
#pragma unroll
    for (int j = 0; j < 4; ++j) {
        int r = r_base + m * 4 + j;
        if (r < N) *(float4*)&H[(size_t)r * 80 + ci] =
            make_float4(acc[j][0], acc[j][1], acc[j][2], acc[j][3]);
        ps[j] = acc[j][0]*asv[0] + acc[j][1]*asv[1] + acc[j][2]*asv[2] + acc[j][3]*asv[3];
        pd[j] = acc[j][0]*adv[0] + acc[j][1]*adv[1] + acc[j][2]*adv[2] + acc[j][3]*adv[3];
        ps[j] += __shfl_xor(ps[j], 16); ps[j] += __shfl_xor(ps[j], 32);
        pd[j] += __shfl_xor(pd[j], 16); pd[j] += __shfl_xor(pd[j], 32);
    }
    if (((tid >> 4) & 3) == 0) {
#pragma unroll
        for (int j = 0; j < 4; ++j) { Ps[w][m][j] = ps[j]; Pd[w][m][j] = pd[j]; }
    }
    __syncthreads();
    if (tid < 64) {
        int r = r_base + tid;
        if (r < N) {
            int mm = tid >> 2, jj = tid & 3;
            H[(size_t)r * 80 + 64] = Ps[0][mm][jj] + Ps[1][mm][jj] + Ps[2][mm][jj] + Ps[3][mm][jj];
            adn[r] = Pd[0][mm][jj] + Pd[1][mm][jj] + Pd[2][mm][jj] + Pd[3][mm][jj];
        }
    }
}

// ---------------- CSR build ----------------
__global__ void count_kernel(const int* __restrict__ dst, int E, int* __restrict__ cnt)
{
    for (int e = blockIdx.x * blockDim.x + threadIdx.x; e < E; e += gridDim.x * blockDim.x)
        atomicAdd(&cnt[dst[e]], 1);
}

__global__ __launch_bounds__(256) void offsets_kernel(
    const int* __restrict__ cnt, int N, int* __restrict__ offv,
    int* __restrict__ fill, int* __restrict__ csr, int* __restrict__ cursor)
{
    int n = blockIdx.x * blockDim.x + threadIdx.x;
    int lane = threadIdx.x & 63;
    int v = (n < N) ? (cnt[n] + 1) : 0;
    int incl = v;
#pragma unroll
    for (int d = 1; d < 64; d <<= 1) {
        int t = __shfl_up(incl, d);
        if (lane >= d) incl += t;
    }
    int total = __shfl(incl, 63);
    int base = 0;
    if (lane == 63) base = atomicAdd(cursor, total);
    base = __shfl(base, 63);
    if (n < N) {
        int o = base + incl - v;
        offv[n] = o;
        csr[o] = n;   // self loop at slot 0
        fill[n] = 1;
    }
}

// dst-partitioned scatter: only edges with dst in [lo,hi) are scattered this pass.
// offv is monotone in node id -> csr writes land in one contiguous L2-resident window.
__global__ void scatter_pass_kernel(const int* __restrict__ src, const int* __restrict__ dst,
                                    int E, int lo, int hi,
                                    const int* __restrict__ offv, int* __restrict__ fill,
                                    int* __restrict__ csr)
{
    for (int e = blockIdx.x * blockDim.x + threadIdx.x; e < E; e += gridDim.x * blockDim.x) {
        int d = dst[e];
        if (d >= lo && d < hi) {
            int pos = offv[d] + atomicAdd(&fill[d], 1);
            csr[pos] = src[e];
        }
    }
}

// ---------------- GAT layer 1: fused single-pass (no max-shift), bias + ELU ----------------
// A rows stride 80: [lane]=h, [64+hh]=alpha_src[head]. Unnormalized p accumulated, 1 div/node.
__global__ __launch_bounds__(256) void gat1_kernel(
    const float* __restrict__ A, const float* __restrict__ adn,
    const float* __restrict__ b1, const int* __restrict__ offv, const int* __restrict__ cnt,
    const int* __restrict__ csr, float* __restrict__ h2, int N)
{
    int n = blockIdx.x * 4 + (threadIdx.x >> 6);
    if (n >= N) return;
    int lane = threadIdx.x & 63;
    int base = offv[n];
    int deg = cnt[n] + 1;
    int hh = lane >> 3;
    float ad = adn[n * 8 + hh];
    float acc = 0.f, psum = 0.f;

    if (deg <= 64) {
        int sreg = csr[base + (lane < deg ? lane : 0)];
        int k = 0;
        for (; k + 4 <= deg; k += 4) {
            const float* r0 = A + (size_t)readlane_i(sreg, k)     * 80;
            const float* r1 = A + (size_t)readlane_i(sreg, k + 1) * 80;
            const float* r2 = A + (size_t)readlane_i(sreg, k + 2) * 80;
            const float* r3 = A + (size_t)readlane_i(sreg, k + 3) * 80;
            float h0 = r0[lane], a0 = r0[64 + hh];
            float h1v = r1[lane], a1 = r1[64 + hh];
            float h2v = r2[lane], a2 = r2[64 + hh];
            float h3 = r3[lane], a3 = r3[64 + hh];
            float p0 = __expf(lrelu(a0 + ad));
            float p1 = __expf(lrelu(a1 + ad));
            float p2 = __expf(lrelu(a2 + ad));
            float p3 = __expf(lrelu(a3 + ad));
            acc += p0 * h0 + p1 * h1v + p2 * h2v + p3 * h3;
            psum += (p0 + p1) + (p2 + p3);
        }
        for (; k < deg; ++k) {
            const float* r = A + (size_t)readlane_i(sreg, k) * 80;
            float p = __expf(lrelu(r[64 + hh] + ad));
            acc += p * r[lane];
            psum += p;
        }
    } else {
        for (int k = 0; k < deg; ++k) {
            int s = __builtin_amdgcn_readfirstlane(csr[base + k]);
            const float* r = A + (size_t)s * 80;
            float p = __expf(lrelu(r[64 + hh] + ad));
            acc += p * r[lane];
            psum += p;
        }
    }
    float v = acc / psum + b1[lane];
    h2[(size_t)n * 64 + lane] = v > 0.f ? v : __expf(v) - 1.f;  // ELU
}

// ---------------- GAT layer 2: fused single-pass, 1 head, bias ----------------
// Z rows stride 80: [lane]=z, [64]=alpha_src. Output dense stride 64.
__global__ __launch_bounds__(256) void gat2_kernel(
    const float* __restrict__ Z, const float* __restrict__ adn,
    const float* __restrict__ b2, const int* __restrict__ offv, const int* __restrict__ cnt,
    const int* __restrict__ csr, float* __restrict__ out, int N)
{
    int n = blockIdx.x * 4 + (threadIdx.x >> 6);
    if (n >= N) return;
    int lane = threadIdx.x & 63;
    int base = offv[n];
    int deg = cnt[n] + 1;
    float ad = adn[n];
    float acc = 0.f, psum = 0.f;

    if (deg <= 64) {
        int sreg = csr[base + (lane < deg ? lane : 0)];
        int k = 0;
        for (; k + 4 <= deg; k += 4) {
            const float* r0 = Z + (size_t)readlane_i(sreg, k)     * 80;
            const float* r1 = Z + (size_t)readlane_i(sreg, k + 1) * 80;
            const float* r2 = Z + (size_t)readlane_i(sreg, k + 2) * 80;
            const float* r3 = Z + (size_t)readlane_i(sreg, k + 3) * 80;
            float z0 = r0[lane], a0 = r0[64];
            float z1 = r1[lane], a1 = r1[64];
            float z2 = r2[lane], a2 = r2[64];
            float z3 = r3[lane], a3 = r3[64];
            float p0 = __expf(lrelu(a0 + ad));
            float p1 = __expf(lrelu(a1 + ad));
            float p2 = __expf(lrelu(a2 + ad));
            float p3 = __expf(lrelu(a3 + ad));
            acc += p0 * z0 + p1 * z1 + p2 * z2 + p3 * z3;
            psum += (p0 + p1) + (p2 + p3);
        }
        for (; k < deg; ++k) {
            const float* r = Z + (size_t)readlane_i(sreg, k) * 80;
            float p = __expf(lrelu(r[64] + ad));
            acc += p * r[lane];
            psum += p;
        }
    } else {
        for (int k = 0; k < deg; ++k) {
            int s = __builtin_amdgcn_readfirstlane(csr[base + k]);
            const float* r = Z + (size_t)s * 80;
            float p = __expf(lrelu(r[64] + ad));
            acc += p * r[lane];
            psum += p;
        }
    }
    out[(size_t)n * 64 + lane] = acc / psum + b2[lane];
}

// ---------------- decode: sigmoid(dot(z2[q0], z2[q1])) ----------------
__global__ __launch_bounds__(256) void decode_kernel(
    const float* __restrict__ z2, const int* __restrict__ q, int Q, float* __restrict__ out)
{
    int i = blockIdx.x * 4 + (threadIdx.x >> 6);
    if (i >= Q) return;
    int lane = threadIdx.x & 63;
    int a = q[i], b = q[Q + i];
    float v = z2[(size_t)a * 64 + lane] * z2[(size_t)b * 64 + lane];
#pragma unroll
    for (int d = 1; d < 64; d <<= 1) v += __shfl_xor(v, d);
    if (lane == 0) out[i] = 1.f / (1.f + __expf(-v));
}

extern "C" void kernel_launch(void* const* d_in, const int* in_sizes, int n_in,
                              void* d_out, int out_size, void* d_ws, size_t ws_size,
                              hipStream_t stream)
{
    const float* x   = (const float*)d_in[0];
    const int*   ei  = (const int*)d_in[1];
    const int*   qe  = (const int*)d_in[2];
    const float* W1  = (const float*)d_in[3];
    const float* as1 = (const float*)d_in[4];
    const float* ad1 = (const float*)d_in[5];
    const float* b1  = (const float*)d_in[6];
    const float* W2  = (const float*)d_in[7];
    const float* as2 = (const float*)d_in[8];
    const float* ad2 = (const float*)d_in[9];
    const float* b2  = (const float*)d_in[10];

    const int N = in_sizes[0] / 128;
    const int E = in_sizes[1] / 2;
    const int Q = in_sizes[2] / 2;

    float* out = (float*)d_out;

    char* ws = (char*)d_ws;
    size_t o = 0;
    auto alloc = [&](size_t bytes) -> void* {
        void* p = ws + o;
        o += (bytes + 255) & ~(size_t)255;
        return p;
    };
    float* bufA  = (float*)alloc((size_t)N * 80 * 4);  // h1+as1 rows, later z+as2 rows
    float* bufB  = (float*)alloc((size_t)N * 64 * 4);  // h2 dense, later final embeddings
    float* adn1  = (float*)alloc((size_t)N * 8 * 4);
    float* adn2  = (float*)alloc((size_t)N * 4);
    int*   cnt   = (int*)alloc((size_t)N * 4);
    int*   offv  = (int*)alloc((size_t)N * 4);
    int*   fill  = (int*)alloc((size_t)N * 4);
    int*   cursor= (int*)alloc(256);
    int*   csr   = (int*)alloc((size_t)(E + N) * 4);

    const int* esrc = ei;
    const int* edst = ei + E;

    hipMemsetAsync(cnt, 0, (size_t)N * 4, stream);
    hipMemsetAsync(cursor, 0, 4, stream);

    int nodeBlocks4 = (N + 3) / 4;
    int tileBlocks  = (N + 63) / 64;
    int edgeBlocks  = (E + 255) / 256;
    int nodeBlocks  = (N + 255) / 256;

    gemm1_kernel<<<tileBlocks, 256, 0, stream>>>(x, W1, as1, ad1, bufA, adn1, N);
    count_kernel<<<edgeBlocks, 256, 0, stream>>>(edst, E, cnt);
    offsets_kernel<<<nodeBlocks, 256, 0, stream>>>(cnt, N, offv, fill, csr, cursor);
    // partitioned scatter: 4 passes, each writing a contiguous L2-resident csr window
    const int P = 4;
    int part = (N + P - 1) / P;
    for (int p = 0; p < P; ++p) {
        int lo = p * part;
        int hi = (p + 1) * part;
        if (hi > N) hi = N;
        scatter_pass_kernel<<<edgeBlocks, 256, 0, stream>>>(esrc, edst, E, lo, hi, offv, fill, csr);
    }
    gat1_kernel<<<nodeBlocks4, 256, 0, stream>>>(bufA, adn1, b1, offv, cnt, csr, bufB, N);
    gemm2_kernel<<<tileBlocks, 256, 0, stream>>>(bufB, W2, as2, ad2, bufA, adn2, N);
    gat2_kernel<<<nodeBlocks4, 256, 0, stream>>>(bufA, adn2, b2, offv, cnt, csr, bufB, N);
    decode_kernel<<<(Q + 3) / 4, 256, 0, stream>>>(bufB, qe, Q, out);
}

// Round 7
// 478.762 us; speedup vs baseline: 1.0970x; 1.0970x over previous
//
#include <hip/hip_runtime.h>
#include <math.h>

constexpr float NEG_SLOPE = 0.2f;

__device__ __forceinline__ float lrelu(float x) { return x > 0.f ? x : NEG_SLOPE * x; }

__device__ __forceinline__ int readlane_i(int v, int l) {
    return __builtin_amdgcn_readlane(v, l);
}
// bf16 pack (RNE) / unpack (exact)
__device__ __forceinline__ unsigned short f2b(float f) {
    unsigned u = __float_as_uint(f);
    unsigned r = u + 0x7FFFu + ((u >> 16) & 1u);
    return (unsigned short)(r >> 16);
}
__device__ __forceinline__ float b2f(unsigned short s) {
    return __uint_as_float((unsigned)s << 16);
}

#define MAC16(av, bv) \
    acc[0][0] += av.x*bv.x; acc[0][1] += av.x*bv.y; acc[0][2] += av.x*bv.z; acc[0][3] += av.x*bv.w; \
    acc[1][0] += av.y*bv.x; acc[1][1] += av.y*bv.y; acc[1][2] += av.y*bv.z; acc[1][3] += av.y*bv.w; \
    acc[2][0] += av.z*bv.x; acc[2][1] += av.z*bv.y; acc[2][2] += av.z*bv.z; acc[2][3] += av.z*bv.w; \
    acc[3][0] += av.w*bv.x; acc[3][1] += av.w*bv.y; acc[3][2] += av.w*bv.z; acc[3][3] += av.w*bv.w;

// ---------------- GEMM1: h1 = x @ W1 (64x64 tile, 4x4/thread) ----------------
// Outputs: Hb bf16 [N,64] (gather table), as1b bf16 [N,8], adn1 f32 [N,8].
__global__ __launch_bounds__(256) void gemm1_kernel(
    const float* __restrict__ X, const float* __restrict__ W,
    const float* __restrict__ a_s, const float* __restrict__ a_d,
    unsigned short* __restrict__ Hb, unsigned short* __restrict__ as1b,
    float* __restrict__ adn, int N)
{
    __shared__ float At[128 * 64];
    __shared__ float Bs[128 * 64];
    const int tid = threadIdx.x;
    const int r_base = blockIdx.x * 64;
    {
        const float4* W4 = (const float4*)W;
        float4* B4 = (float4*)Bs;
#pragma unroll
        for (int it = 0; it < 8; ++it) B4[tid + it * 256] = W4[tid + it * 256];
    }
    {
        const float4* X4 = (const float4*)X;
#pragma unroll
        for (int it = 0; it < 2; ++it) {
            int t = tid + it * 256;          // 512 tasks: 4x4 block transpose
            int rg = t & 15, cg = t >> 4;    // rg: row quad, cg: k quad (0..31)
            float4 rw[4];
#pragma unroll
            for (int j = 0; j < 4; ++j) {
                int r = r_base + rg * 4 + j;
                rw[j] = (r < N) ? X4[(size_t)r * 32 + cg] : make_float4(0.f, 0.f, 0.f, 0.f);
            }
            int rsw = 4 * (rg ^ (cg & 15));
            int k0 = cg * 4;
            *(float4*)&At[(k0    ) * 64 + rsw] = make_float4(rw[0].x, rw[1].x, rw[2].x, rw[3].x);
            *(float4*)&At[(k0 + 1) * 64 + rsw] = make_float4(rw[0].y, rw[1].y, rw[2].y, rw[3].y);
            *(float4*)&At[(k0 + 2) * 64 + rsw] = make_float4(rw[0].z, rw[1].z, rw[2].z, rw[3].z);
            *(float4*)&At[(k0 + 3) * 64 + rsw] = make_float4(rw[0].w, rw[1].w, rw[2].w, rw[3].w);
        }
    }
    __syncthreads();
    const int m  = tid & 15;
    const int ci = (tid >> 4) * 4;
    float acc[4][4] = {};
#pragma unroll 4
    for (int kq = 0; kq < 32; ++kq) {
        int aoff = kq * 256 + 4 * (m ^ (kq & 15));
        int boff = kq * 256 + ci;
        float4 a0 = *(const float4*)&At[aoff];
        float4 a1 = *(const float4*)&At[aoff + 64];
        float4 a2 = *(const float4*)&At[aoff + 128];
        float4 a3 = *(const float4*)&At[aoff + 192];
        float4 b0 = *(const float4*)&Bs[boff];
        float4 b1 = *(const float4*)&Bs[boff + 64];
        float4 b2 = *(const float4*)&Bs[boff + 128];
        float4 b3 = *(const float4*)&Bs[boff + 192];
        MAC16(a0, b0); MAC16(a1, b1); MAC16(a2, b2); MAC16(a3, b3);
    }
    float asv[4] = {a_s[ci], a_s[ci + 1], a_s[ci + 2], a_s[ci + 3]};
    float adv[4] = {a_d[ci], a_d[ci + 1], a_d[ci + 2], a_d[ci + 3]};
    int head = ci >> 3;
    bool owner = ((tid >> 4) & 1) == 0;
#pragma unroll
    for (int j = 0; j < 4; ++j) {
        int r = r_base + m * 4 + j;
        if (r < N) {
            ushort4 pk;
            pk.x = f2b(acc[j][0]); pk.y = f2b(acc[j][1]);
            pk.z = f2b(acc[j][2]); pk.w = f2b(acc[j][3]);
            *(ushort4*)&Hb[(size_t)r * 64 + ci] = pk;
        }
        float ps = acc[j][0]*asv[0] + acc[j][1]*asv[1] + acc[j][2]*asv[2] + acc[j][3]*asv[3];
        float pd = acc[j][0]*adv[0] + acc[j][1]*adv[1] + acc[j][2]*adv[2] + acc[j][3]*adv[3];
        ps += __shfl_xor(ps, 16);
        pd += __shfl_xor(pd, 16);
        if (owner && r < N) { as1b[r * 8 + head] = f2b(ps); adn[r * 8 + head] = pd; }
    }
}

// ---------------- GEMM2: z = h2 @ W2 (64x64 tile) ----------------
// X dense f32 [N,64]; outputs Zb bf16 [N,64], as2b bf16 [N], adn2 f32 [N].
__global__ __launch_bounds__(256) void gemm2_kernel(
    const float* __restrict__ X, const float* __restrict__ W,
    const float* __restrict__ a_s, const float* __restrict__ a_d,
    unsigned short* __restrict__ Zb, unsigned short* __restrict__ as2b,
    float* __restrict__ adn, int N)
{
    __shared__ float At[64 * 64];
    __shared__ float Bs[64 * 64];
    __shared__ float Ps[4][16][4], Pd[4][16][4];
    const int tid = threadIdx.x;
    const int r_base = blockIdx.x * 64;
    {
        const float4* W4 = (const float4*)W;
        float4* B4 = (float4*)Bs;
#pragma unroll
        for (int it = 0; it < 4; ++it) B4[tid + it * 256] = W4[tid + it * 256];
    }
    {
        const float4* X4 = (const float4*)X;
        int rg = tid & 15, cg = tid >> 4;    // cg 0..15
        float4 rw[4];
#pragma unroll
        for (int j = 0; j < 4; ++j) {
            int r = r_base + rg * 4 + j;
            rw[j] = (r < N) ? X4[(size_t)r * 16 + cg] : make_float4(0.f, 0.f, 0.f, 0.f);
        }
        int rsw = 4 * (rg ^ (cg & 15));
        int k0 = cg * 4;
        *(float4*)&At[(k0    ) * 64 + rsw] = make_float4(rw[0].x, rw[1].x, rw[2].x, rw[3].x);
        *(float4*)&At[(k0 + 1) * 64 + rsw] = make_float4(rw[0].y, rw[1].y, rw[2].y, rw[3].y);
        *(float4*)&At[(k0 + 2) * 64 + rsw] = make_float4(rw[0].z, rw[1].z, rw[2].z, rw[3].z);
        *(float4*)&At[(k0 + 3) * 64 + rsw] = make_float4(rw[0].w, rw[1].w, rw[2].w, rw[3].w);
    }
    __syncthreads();
    const int m  = tid & 15;
    const int ci = (tid >> 4) * 4;
    float acc[4][4] = {};
#pragma unroll 4
    for (int kq = 0; kq < 16; ++kq) {
        int aoff = kq * 256 + 4 * (m ^ (kq & 15));
        int boff = kq * 256 + ci;
        float4 a0 = *(const float4*)&At[aoff];
        float4 a1 = *(const float4*)&At[aoff + 64];
        float4 a2 = *(const float4*)&At[aoff + 128];
        float4 a3 = *(const float4*)&At[aoff + 192];
        float4 b0 = *(const float4*)&Bs[boff];
        float4 b1 = *(const float4*)&Bs[boff + 64];
        float4 b2 = *(const float4*)&Bs[boff + 128];
        float4 b3 = *(const float4*)&Bs[boff + 192];
        MAC16(a0, b0); MAC16(a1, b1); MAC16(a2, b2); MAC16(a3, b3);
    }
    float asv[4] = {a_s[ci], a_s[ci + 1], a_s[ci + 2], a_s[ci + 3]};
    float adv[4] = {a_d[ci], a_d[ci + 1], a_d[ci + 2], a_d[ci + 3]};
    int w = tid >> 6;
    float ps[4], pd[4];
#pragma unroll
    for (int j = 0; j < 4; ++j) {
        int r = r_base + m * 4 + j;
        if (r < N) {
            ushort4 pk;
            pk.x = f2b(acc[j][0]); pk.y = f2b(acc[j][1]);
            pk.z = f2b(acc[j][2]); pk.w = f2b(acc[j][3]);
            *(ushort4*)&Zb[(size_t)r * 64 + ci] = pk;
        }
        ps[j] = acc[j][0]*asv[0] + acc[j][1]*asv[1] + acc[j][2]*asv[2] + acc[j][3]*asv[3];
        pd[j] = acc[j][0]*adv[0] + acc[j][1]*adv[1] + acc[j][2]*adv[2] + acc[j][3]*adv[3];
        ps[j] += __shfl_xor(ps[j], 16); ps[j] += __shfl_xor(ps[j], 32);
        pd[j] += __shfl_xor(pd[j], 16); pd[j] += __shfl_xor(pd[j], 32);
    }
    if (((tid >> 4) & 3) == 0) {
#pragma unroll
        for (int j = 0; j < 4; ++j) { Ps[w][m][j] = ps[j]; Pd[w][m][j] = pd[j]; }
    }
    __syncthreads();
    if (tid < 64) {
        int r = r_base + tid;
        if (r < N) {
            int mm = tid >> 2, jj = tid & 3;
            as2b[r] = f2b(Ps[0][mm][jj] + Ps[1][mm][jj] + Ps[2][mm][jj] + Ps[3][mm][jj]);
            adn[r]  = Pd[0][mm][jj] + Pd[1][mm][jj] + Pd[2][mm][jj] + Pd[3][mm][jj];
        }
    }
}

// ---------------- CSR build (proven replay-safe) ----------------
__global__ void count_kernel(const int* __restrict__ dst, int E, int* __restrict__ cnt)
{
    for (int e = blockIdx.x * blockDim.x + threadIdx.x; e < E; e += gridDim.x * blockDim.x)
        atomicAdd(&cnt[dst[e]], 1);
}

__global__ __launch_bounds__(256) void offsets_kernel(
    const int* __restrict__ cnt, int N, int* __restrict__ offv,
    int* __restrict__ fill, int* __restrict__ csr, int* __restrict__ cursor)
{
    int n = blockIdx.x * blockDim.x + threadIdx.x;
    int lane = threadIdx.x & 63;
    int v = (n < N) ? (cnt[n] + 1) : 0;
    int incl = v;
#pragma unroll
    for (int d = 1; d < 64; d <<= 1) {
        int t = __shfl_up(incl, d);
        if (lane >= d) incl += t;
    }
    int total = __shfl(incl, 63);
    int base = 0;
    if (lane == 63) base = atomicAdd(cursor, total);
    base = __shfl(base, 63);
    if (n < N) {
        int o = base + incl - v;
        offv[n] = o;
        csr[o] = n;   // self loop at slot 0
        fill[n] = 1;
    }
}

__global__ void scatter_kernel(const int* __restrict__ src, const int* __restrict__ dst, int E,
                               const int* __restrict__ offv, int* __restrict__ fill,
                               int* __restrict__ csr)
{
    for (int e = blockIdx.x * blockDim.x + threadIdx.x; e < E; e += gridDim.x * blockDim.x) {
        int d = dst[e];
        int pos = offv[d] + atomicAdd(&fill[d], 1);
        csr[pos] = src[e];
    }
}

// ---------------- GAT layer 1: bf16 gather, fused single-pass, bias + ELU ----------------
__global__ __launch_bounds__(256) void gat1_kernel(
    const unsigned short* __restrict__ Hb, const unsigned short* __restrict__ as1b,
    const float* __restrict__ adn, const float* __restrict__ b1,
    const int* __restrict__ offv, const int* __restrict__ cnt,
    const int* __restrict__ csr, float* __restrict__ h2, int N)
{
    int n = blockIdx.x * 4 + (threadIdx.x >> 6);
    if (n >= N) return;
    int lane = threadIdx.x & 63;
    int base = offv[n];
    int deg = cnt[n] + 1;
    int hh = lane >> 3;
    float ad = adn[n * 8 + hh];
    float acc = 0.f, psum = 0.f;

    if (deg <= 64) {
        int sreg = csr[base + (lane < deg ? lane : 0)];
        int k = 0;
        for (; k + 4 <= deg; k += 4) {
            int s0 = readlane_i(sreg, k), s1 = readlane_i(sreg, k + 1),
                s2 = readlane_i(sreg, k + 2), s3 = readlane_i(sreg, k + 3);
            float h0 = b2f(Hb[(size_t)s0 * 64 + lane]), a0 = b2f(as1b[s0 * 8 + hh]);
            float h1v = b2f(Hb[(size_t)s1 * 64 + lane]), a1 = b2f(as1b[s1 * 8 + hh]);
            float h2v = b2f(Hb[(size_t)s2 * 64 + lane]), a2 = b2f(as1b[s2 * 8 + hh]);
            float h3 = b2f(Hb[(size_t)s3 * 64 + lane]), a3 = b2f(as1b[s3 * 8 + hh]);
            float p0 = __expf(lrelu(a0 + ad));
            float p1 = __expf(lrelu(a1 + ad));
            float p2 = __expf(lrelu(a2 + ad));
            float p3 = __expf(lrelu(a3 + ad));
            acc += p0 * h0 + p1 * h1v + p2 * h2v + p3 * h3;
            psum += (p0 + p1) + (p2 + p3);
        }
        for (; k < deg; ++k) {
            int s = readlane_i(sreg, k);
            float p = __expf(lrelu(b2f(as1b[s * 8 + hh]) + ad));
            acc += p * b2f(Hb[(size_t)s * 64 + lane]);
            psum += p;
        }
    } else {
        for (int k = 0; k < deg; ++k) {
            int s = __builtin_amdgcn_readfirstlane(csr[base + k]);
            float p = __expf(lrelu(b2f(as1b[s * 8 + hh]) + ad));
            acc += p * b2f(Hb[(size_t)s * 64 + lane]);
            psum += p;
        }
    }
    float v = acc / psum + b1[lane];
    h2[(size_t)n * 64 + lane] = v > 0.f ? v : __expf(v) - 1.f;  // ELU
}

// ---------------- GAT layer 2: bf16 gather, 1 head, bias; f32 output ----------------
__global__ __launch_bounds__(256) void gat2_kernel(
    const unsigned short* __restrict__ Zb, const unsigned short* __restrict__ as2b,
    const float* __restrict__ adn, const float* __restrict__ b2,
    const int* __restrict__ offv, const int* __restrict__ cnt,
    const int* __restrict__ csr, float* __restrict__ out, int N)
{
    int n = blockIdx.x * 4 + (threadIdx.x >> 6);
    if (n >= N) return;
    int lane = threadIdx.x & 63;
    int base = offv[n];
    int deg = cnt[n] + 1;
    float ad = adn[n];
    float acc = 0.f, psum = 0.f;

    if (deg <= 64) {
        int sreg = csr[base + (lane < deg ? lane : 0)];
        int k = 0;
        for (; k + 4 <= deg; k += 4) {
            int s0 = readlane_i(sreg, k), s1 = readlane_i(sreg, k + 1),
                s2 = readlane_i(sreg, k + 2), s3 = readlane_i(sreg, k + 3);
            float z0 = b2f(Zb[(size_t)s0 * 64 + lane]), a0 = b2f(as2b[s0]);
            float z1 = b2f(Zb[(size_t)s1 * 64 + lane]), a1 = b2f(as2b[s1]);
            float z2 = b2f(Zb[(size_t)s2 * 64 + lane]), a2 = b2f(as2b[s2]);
            float z3 = b2f(Zb[(size_t)s3 * 64 + lane]), a3 = b2f(as2b[s3]);
            float p0 = __expf(lrelu(a0 + ad));
            float p1 = __expf(lrelu(a1 + ad));
            float p2 = __expf(lrelu(a2 + ad));
            float p3 = __expf(lrelu(a3 + ad));
            acc += p0 * z0 + p1 * z1 + p2 * z2 + p3 * z3;
            psum += (p0 + p1) + (p2 + p3);
        }
        for (; k < deg; ++k) {
            int s = readlane_i(sreg, k);
            float p = __expf(lrelu(b2f(as2b[s]) + ad));
            acc += p * b2f(Zb[(size_t)s * 64 + lane]);
            psum += p;
        }
    } else {
        for (int k = 0; k < deg; ++k) {
            int s = __builtin_amdgcn_readfirstlane(csr[base + k]);
            float p = __expf(lrelu(b2f(as2b[s]) + ad));
            acc += p * b2f(Zb[(size_t)s * 64 + lane]);
            psum += p;
        }
    }
    out[(size_t)n * 64 + lane] = acc / psum + b2[lane];
}

// ---------------- decode: sigmoid(dot(z2[q0], z2[q1])) ----------------
__global__ __launch_bounds__(256) void decode_kernel(
    const float* __restrict__ z2, const int* __restrict__ q, int Q, float* __restrict__ out)
{
    int i = blockIdx.x * 4 + (threadIdx.x >> 6);
    if (i >= Q) return;
    int lane = threadIdx.x & 63;
    int a = q[i], b = q[Q + i];
    float v = z2[(size_t)a * 64 + lane] * z2[(size_t)b * 64 + lane];
#pragma unroll
    for (int d = 1; d < 64; d <<= 1) v += __shfl_xor(v, d);
    if (lane == 0) out[i] = 1.f / (1.f + __expf(-v));
}

extern "C" void kernel_launch(void* const* d_in, const int* in_sizes, int n_in,
                              void* d_out, int out_size, void* d_ws, size_t ws_size,
                              hipStream_t stream)
{
    const float* x   = (const float*)d_in[0];
    const int*   ei  = (const int*)d_in[1];
    const int*   qe  = (const int*)d_in[2];
    const float* W1  = (const float*)d_in[3];
    const float* as1 = (const float*)d_in[4];
    const float* ad1 = (const float*)d_in[5];
    const float* b1  = (const float*)d_in[6];
    const float* W2  = (const float*)d_in[7];
    const float* as2 = (const float*)d_in[8];
    const float* ad2 = (const float*)d_in[9];
    const float* b2  = (const float*)d_in[10];

    const int N = in_sizes[0] / 128;
    const int E = in_sizes[1] / 2;
    const int Q = in_sizes[2] / 2;

    float* out = (float*)d_out;

    char* ws = (char*)d_ws;
    size_t o = 0;
    auto alloc = [&](size_t bytes) -> void* {
        void* p = ws + o;
        o += (bytes + 255) & ~(size_t)255;
        return p;
    };
    unsigned short* hb   = (unsigned short*)alloc((size_t)N * 64 * 2); // h1 bf16, later z bf16
    float* f32buf        = (float*)alloc((size_t)N * 64 * 4);          // h2 f32, later z2 f32
    unsigned short* as1b = (unsigned short*)alloc((size_t)N * 8 * 2);
    float* adn1          = (float*)alloc((size_t)N * 8 * 4);
    unsigned short* as2b = (unsigned short*)alloc((size_t)N * 2);
    float* adn2          = (float*)alloc((size_t)N * 4);
    int*   cnt    = (int*)alloc((size_t)N * 4);
    int*   offv   = (int*)alloc((size_t)N * 4);
    int*   fill   = (int*)alloc((size_t)N * 4);
    int*   cursor = (int*)alloc(256);
    int*   csr    = (int*)alloc((size_t)(E + N) * 4);

    const int* esrc = ei;
    const int* edst = ei + E;

    hipMemsetAsync(cnt, 0, (size_t)N * 4, stream);
    hipMemsetAsync(cursor, 0, 4, stream);

    int nodeBlocks4 = (N + 3) / 4;
    int tileBlocks  = (N + 63) / 64;
    int edgeBlocks  = (E + 255) / 256;
    int nodeBlocks  = (N + 255) / 256;

    gemm1_kernel<<<tileBlocks, 256, 0, stream>>>(x, W1, as1, ad1, hb, as1b, adn1, N);
    count_kernel<<<edgeBlocks, 256, 0, stream>>>(edst, E, cnt);
    offsets_kernel<<<nodeBlocks, 256, 0, stream>>>(cnt, N, offv, fill, csr, cursor);
    scatter_kernel<<<edgeBlocks, 256, 0, stream>>>(esrc, edst, E, offv, fill, csr);
    gat1_kernel<<<nodeBlocks4, 256, 0, stream>>>(hb, as1b, adn1, b1, offv, cnt, csr, f32buf, N);
    gemm2_kernel<<<tileBlocks, 256, 0, stream>>>(f32buf, W2, as2, ad2, hb, as2b, adn2, N);
    gat2_kernel<<<nodeBlocks4, 256, 0, stream>>>(hb, as2b, adn2, b2, offv, cnt, csr, f32buf, N);
    decode_kernel<<<(Q + 3) / 4, 256, 0, stream>>>(f32buf, qe, Q, out);
}

// Round 8
// 474.706 us; speedup vs baseline: 1.1064x; 1.0085x over previous
//
#include <hip/hip_runtime.h>
#include <math.h>

constexpr float NEG_SLOPE = 0.2f;

__device__ __forceinline__ float lrelu(float x) { return x > 0.f ? x : NEG_SLOPE * x; }

__device__ __forceinline__ int readlane_i(int v, int l) {
    return __builtin_amdgcn_readlane(v, l);
}
// bf16 pack (RNE) / unpack (exact)
__device__ __forceinline__ unsigned short f2b(float f) {
    unsigned u = __float_as_uint(f);
    unsigned r = u + 0x7FFFu + ((u >> 16) & 1u);
    return (unsigned short)(r >> 16);
}
__device__ __forceinline__ float b2f(unsigned short s) {
    return __uint_as_float((unsigned)s << 16);
}

#define MAC16(av, bv) \
    acc[0][0] += av.x*bv.x; acc[0][1] += av.x*bv.y; acc[0][2] += av.x*bv.z; acc[0][3] += av.x*bv.w; \
    acc[1][0] += av.y*bv.x; acc[1][1] += av.y*bv.y; acc[1][2] += av.y*bv.z; acc[1][3] += av.y*bv.w; \
    acc[2][0] += av.z*bv.x; acc[2][1] += av.z*bv.y; acc[2][2] += av.z*bv.z; acc[2][3] += av.z*bv.w; \
    acc[3][0] += av.w*bv.x; acc[3][1] += av.w*bv.y; acc[3][2] += av.w*bv.z; acc[3][3] += av.w*bv.w;

// ---------------- GEMM1: h1 = x @ W1 (64x64 tile, 4x4/thread) ----------------
__global__ __launch_bounds__(256) void gemm1_kernel(
    const float* __restrict__ X, const float* __restrict__ W,
    const float* __restrict__ a_s, const float* __restrict__ a_d,
    unsigned short* __restrict__ Hb, unsigned short* __restrict__ as1b,
    float* __restrict__ adn, int N)
{
    __shared__ float At[128 * 64];
    __shared__ float Bs[128 * 64];
    const int tid = threadIdx.x;
    const int r_base = blockIdx.x * 64;
    {
        const float4* W4 = (const float4*)W;
        float4* B4 = (float4*)Bs;
#pragma unroll
        for (int it = 0; it < 8; ++it) B4[tid + it * 256] = W4[tid + it * 256];
    }
    {
        const float4* X4 = (const float4*)X;
#pragma unroll
        for (int it = 0; it < 2; ++it) {
            int t = tid + it * 256;
            int rg = t & 15, cg = t >> 4;
            float4 rw[4];
#pragma unroll
            for (int j = 0; j < 4; ++j) {
                int r = r_base + rg * 4 + j;
                rw[j] = (r < N) ? X4[(size_t)r * 32 + cg] : make_float4(0.f, 0.f, 0.f, 0.f);
            }
            int rsw = 4 * (rg ^ (cg & 15));
            int k0 = cg * 4;
            *(float4*)&At[(k0    ) * 64 + rsw] = make_float4(rw[0].x, rw[1].x, rw[2].x, rw[3].x);
            *(float4*)&At[(k0 + 1) * 64 + rsw] = make_float4(rw[0].y, rw[1].y, rw[2].y, rw[3].y);
            *(float4*)&At[(k0 + 2) * 64 + rsw] = make_float4(rw[0].z, rw[1].z, rw[2].z, rw[3].z);
            *(float4*)&At[(k0 + 3) * 64 + rsw] = make_float4(rw[0].w, rw[1].w, rw[2].w, rw[3].w);
        }
    }
    __syncthreads();
    const int m  = tid & 15;
    const int ci = (tid >> 4) * 4;
    float acc[4][4] = {};
#pragma unroll 4
    for (int kq = 0; kq < 32; ++kq) {
        int aoff = kq * 256 + 4 * (m ^ (kq & 15));
        int boff = kq * 256 + ci;
        float4 a0 = *(const float4*)&At[aoff];
        float4 a1 = *(const float4*)&At[aoff + 64];
        float4 a2 = *(const float4*)&At[aoff + 128];
        float4 a3 = *(const float4*)&At[aoff + 192];
        float4 b0 = *(const float4*)&Bs[boff];
        float4 b1 = *(const float4*)&Bs[boff + 64];
        float4 b2 = *(const float4*)&Bs[boff + 128];
        float4 b3 = *(const float4*)&Bs[boff + 192];
        MAC16(a0, b0); MAC16(a1, b1); MAC16(a2, b2); MAC16(a3, b3);
    }
    float asv[4] = {a_s[ci], a_s[ci + 1], a_s[ci + 2], a_s[ci + 3]};
    float adv[4] = {a_d[ci], a_d[ci + 1], a_d[ci + 2], a_d[ci + 3]};
    int head = ci >> 3;
    bool owner = ((tid >> 4) & 1) == 0;
#pragma unroll
    for (int j = 0; j < 4; ++j) {
        int r = r_base + m * 4 + j;
        if (r < N) {
            ushort4 pk;
            pk.x = f2b(acc[j][0]); pk.y = f2b(acc[j][1]);
            pk.z = f2b(acc[j][2]); pk.w = f2b(acc[j][3]);
            *(ushort4*)&Hb[(size_t)r * 64 + ci] = pk;
        }
        float ps = acc[j][0]*asv[0] + acc[j][1]*asv[1] + acc[j][2]*asv[2] + acc[j][3]*asv[3];
        float pd = acc[j][0]*adv[0] + acc[j][1]*adv[1] + acc[j][2]*adv[2] + acc[j][3]*adv[3];
        ps += __shfl_xor(ps, 16);
        pd += __shfl_xor(pd, 16);
        if (owner && r < N) { as1b[r * 8 + head] = f2b(ps); adn[r * 8 + head] = pd; }
    }
}

// ---------------- GEMM2: z = h2 @ W2 (64x64 tile) ----------------
__global__ __launch_bounds__(256) void gemm2_kernel(
    const float* __restrict__ X, const float* __restrict__ W,
    const float* __restrict__ a_s, const float* __restrict__ a_d,
    unsigned short* __restrict__ Zb, unsigned short* __restrict__ as2b,
    float* __restrict__ adn, int N)
{
    __shared__ float At[64 * 64];
    __shared__ float Bs[64 * 64];
    __shared__ float Ps[4][16][4], Pd[4][16][4];
    const int tid = threadIdx.x;
    const int r_base = blockIdx.x * 64;
    {
        const float4* W4 = (const float4*)W;
        float4* B4 = (float4*)Bs;
#pragma unroll
        for (int it = 0; it < 4; ++it) B4[tid + it * 256] = W4[tid + it * 256];
    }
    {
        const float4* X4 = (const float4*)X;
        int rg = tid & 15, cg = tid >> 4;
        float4 rw[4];
#pragma unroll
        for (int j = 0; j < 4; ++j) {
            int r = r_base + rg * 4 + j;
            rw[j] = (r < N) ? X4[(size_t)r * 16 + cg] : make_float4(0.f, 0.f, 0.f, 0.f);
        }
        int rsw = 4 * (rg ^ (cg & 15));
        int k0 = cg * 4;
        *(float4*)&At[(k0    ) * 64 + rsw] = make_float4(rw[0].x, rw[1].x, rw[2].x, rw[3].x);
        *(float4*)&At[(k0 + 1) * 64 + rsw] = make_float4(rw[0].y, rw[1].y, rw[2].y, rw[3].y);
        *(float4*)&At[(k0 + 2) * 64 + rsw] = make_float4(rw[0].z, rw[1].z, rw[2].z, rw[3].z);
        *(float4*)&At[(k0 + 3) * 64 + rsw] = make_float4(rw[0].w, rw[1].w, rw[2].w, rw[3].w);
    }
    __syncthreads();
    const int m  = tid & 15;
    const int ci = (tid >> 4) * 4;
    float acc[4][4] = {};
#pragma unroll 4
    for (int kq = 0; kq < 16; ++kq) {
        int aoff = kq * 256 + 4 * (m ^ (kq & 15));
        int boff = kq * 256 + ci;
        float4 a0 = *(const float4*)&At[aoff];
        float4 a1 = *(const float4*)&At[aoff + 64];
        float4 a2 = *(const float4*)&At[aoff + 128];
        float4 a3 = *(const float4*)&At[aoff + 192];
        float4 b0 = *(const float4*)&Bs[boff];
        float4 b1 = *(const float4*)&Bs[boff + 64];
        float4 b2 = *(const float4*)&Bs[boff + 128];
        float4 b3 = *(const float4*)&Bs[boff + 192];
        MAC16(a0, b0); MAC16(a1, b1); MAC16(a2, b2); MAC16(a3, b3);
    }
    float asv[4] = {a_s[ci], a_s[ci + 1], a_s[ci + 2], a_s[ci + 3]};
    float adv[4] = {a_d[ci], a_d[ci + 1], a_d[ci + 2], a_d[ci + 3]};
    int w = tid >> 6;
    float ps[4], pd[4];
#pragma unroll
    for (int j = 0; j < 4; ++j) {
        int r = r_base + m * 4 + j;
        if (r < N) {
            ushort4 pk;
            pk.x = f2b(acc[j][0]); pk.y = f2b(acc[j][1]);
            pk.z = f2b(acc[j][2]); pk.w = f2b(acc[j][3]);
            *(ushort4*)&Zb[(size_t)r * 64 + ci] = pk;
        }
        ps[j] = acc[j][0]*asv[0] + acc[j][1]*asv[1] + acc[j][2]*asv[2] + acc[j][3]*asv[3];
        pd[j] = acc[j][0]*adv[0] + acc[j][1]*adv[1] + acc[j][2]*adv[2] + acc[j][3]*adv[3];
        ps[j] += __shfl_xor(ps[j], 16); ps[j] += __shfl_xor(ps[j], 32);
        pd[j] += __shfl_xor(pd[j], 16); pd[j] += __shfl_xor(pd[j], 32);
    }
    if (((tid >> 4) & 3) == 0) {
#pragma unroll
        for (int j = 0; j < 4; ++j) { Ps[w][m][j] = ps[j]; Pd[w][m][j] = pd[j]; }
    }
    __syncthreads();
    if (tid < 64) {
        int r = r_base + tid;
        if (r < N) {
            int mm = tid >> 2, jj = tid & 3;
            as2b[r] = f2b(Ps[0][mm][jj] + Ps[1][mm][jj] + Ps[2][mm][jj] + Ps[3][mm][jj]);
            adn[r]  = Pd[0][mm][jj] + Pd[1][mm][jj] + Pd[2][mm][jj] + Pd[3][mm][jj];
        }
    }
}

// ================= Tile-stable bucketed CSR build =================
// shift=9 (512-node buckets), T=4096-edge tiles. All outputs fully rewritten
// each launch by statically-assigned blocks; no cross-launch state, no memsets.

// S1: per-tile histogram (plain stores, deterministic)
__global__ __launch_bounds__(256) void bhist_kernel(
    const int* __restrict__ dst, int E, int T, int shift, int NB,
    int* __restrict__ thist)
{
    __shared__ int h[256];
    int t = blockIdx.x, tid = threadIdx.x;
    for (int i = tid; i < NB; i += 256) h[i] = 0;
    __syncthreads();
    int e0 = t * T, e1 = min(E, e0 + T);
    for (int e = e0 + tid; e < e1; e += 256) atomicAdd(&h[dst[e] >> shift], 1);
    __syncthreads();
    for (int i = tid; i < NB; i += 256) thist[(size_t)t * NB + i] = h[i];
}

// S2: bucket totals -> exclusive bbase; thist -> absolute (tile,bucket) offsets
__global__ __launch_bounds__(256) void bscan_kernel(
    int* __restrict__ thist, int NT, int NB, int* __restrict__ bbase)
{
    __shared__ int btot[256];
    __shared__ int bb[257];
    int tid = threadIdx.x;
    for (int b = tid; b < NB; b += 256) {
        int tot = 0;
        for (int t = 0; t < NT; ++t) tot += thist[(size_t)t * NB + b];
        btot[b] = tot;
    }
    __syncthreads();
    if (tid < 64) {
        int carry = 0;
        for (int base = 0; base < NB; base += 64) {
            int i = base + tid;
            int v = (i < NB) ? btot[i] : 0;
            int incl = v;
#pragma unroll
            for (int d = 1; d < 64; d <<= 1) {
                int t2 = __shfl_up(incl, d);
                if (tid >= d) incl += t2;
            }
            if (i < NB) bb[i] = carry + incl - v;
            carry += __shfl(incl, 63);
        }
        if (tid == 0) bb[NB] = carry;
    }
    __syncthreads();
    for (int b = tid; b <= NB; b += 256) bbase[b] = bb[b];
    for (int b = tid; b < NB; b += 256) {
        int run = bb[b];
        for (int t = 0; t < NT; ++t) {
            int tmp = thist[(size_t)t * NB + b];
            thist[(size_t)t * NB + b] = run;
            run += tmp;
        }
    }
}

// S3: scatter (src,dst) pairs into bucket-major staging; segment-contiguous writes
__global__ __launch_bounds__(256) void bscatter_kernel(
    const int* __restrict__ src, const int* __restrict__ dst, int E, int T,
    int shift, int NB, const int* __restrict__ thist, int2* __restrict__ stg)
{
    __shared__ int cur[256];
    int t = blockIdx.x, tid = threadIdx.x;
    for (int i = tid; i < NB; i += 256) cur[i] = thist[(size_t)t * NB + i];
    __syncthreads();
    int e0 = t * T, e1 = min(E, e0 + T);
    for (int e = e0 + tid; e < e1; e += 256) {
        int d = dst[e];
        int pos = atomicAdd(&cur[d >> shift], 1);
        stg[pos] = make_int2(src[e], d);
    }
}

// S4: per-bucket: counts -> scan -> offv/cnt/csr (self-loop at slot 0), dense window
__global__ __launch_bounds__(256) void bbuild_kernel(
    const int2* __restrict__ stg, const int* __restrict__ bbase, int shift, int N,
    int* __restrict__ offv, int* __restrict__ cnt, int* __restrict__ csr)
{
    __shared__ int lcnt[1024], loff[1024], lfill[1024];
    int b = blockIdx.x, tid = threadIdx.x;
    int bs = 1 << shift;
    int n0 = b << shift;
    int e0 = bbase[b], e1 = bbase[b + 1];
    for (int i = tid; i < bs; i += 256) lcnt[i] = 0;
    __syncthreads();
    for (int e = e0 + tid; e < e1; e += 256) atomicAdd(&lcnt[stg[e].y - n0], 1);
    __syncthreads();
    if (tid < 64) {
        int seg = bs >> 6;
        int j0 = tid * seg;
        int local = 0;
        for (int j = 0; j < seg; ++j) {
            int n = n0 + j0 + j;
            local += (n < N) ? lcnt[j0 + j] + 1 : 0;
        }
        int incl = local;
#pragma unroll
        for (int d = 1; d < 64; d <<= 1) {
            int t2 = __shfl_up(incl, d);
            if (tid >= d) incl += t2;
        }
        int run = incl - local;
        for (int j = 0; j < seg; ++j) {
            int n = n0 + j0 + j;
            int v = (n < N) ? lcnt[j0 + j] + 1 : 0;
            loff[j0 + j] = run;
            run += v;
        }
    }
    __syncthreads();
    int csr_base = e0 + n0;   // edges before bucket + self-loops before bucket
    for (int i = tid; i < bs; i += 256) {
        int n = n0 + i;
        if (n < N) {
            int o = csr_base + loff[i];
            offv[n] = o;
            cnt[n] = lcnt[i];
            csr[o] = n;          // self loop at slot 0
            lfill[i] = loff[i] + 1;
        }
    }
    __syncthreads();
    for (int e = e0 + tid; e < e1; e += 256) {
        int2 p = stg[e];
        int pos = atomicAdd(&lfill[p.y - n0], 1);
        csr[csr_base + pos] = p.x;
    }
}

// ---------------- GAT layer 1: bf16 gather, fused single-pass, bias + ELU ----------------
__global__ __launch_bounds__(256) void gat1_kernel(
    const unsigned short* __restrict__ Hb, const unsigned short* __restrict__ as1b,
    const float* __restrict__ adn, const float* __restrict__ b1,
    const int* __restrict__ offv, const int* __restrict__ cnt,
    const int* __restrict__ csr, float* __restrict__ h2, int N)
{
    int n = blockIdx.x * 4 + (threadIdx.x >> 6);
    if (n >= N) return;
    int lane = threadIdx.x & 63;
    int base = offv[n];
    int deg = cnt[n] + 1;
    int hh = lane >> 3;
    float ad = adn[n * 8 + hh];
    float acc = 0.f, psum = 0.f;

    if (deg <= 64) {
        int sreg = csr[base + (lane < deg ? lane : 0)];
        int k = 0;
        for (; k + 4 <= deg; k += 4) {
            int s0 = readlane_i(sreg, k), s1 = readlane_i(sreg, k + 1),
                s2 = readlane_i(sreg, k + 2), s3 = readlane_i(sreg, k + 3);
            float h0 = b2f(Hb[(size_t)s0 * 64 + lane]), a0 = b2f(as1b[s0 * 8 + hh]);
            float h1v = b2f(Hb[(size_t)s1 * 64 + lane]), a1 = b2f(as1b[s1 * 8 + hh]);
            float h2v = b2f(Hb[(size_t)s2 * 64 + lane]), a2 = b2f(as1b[s2 * 8 + hh]);
            float h3 = b2f(Hb[(size_t)s3 * 64 + lane]), a3 = b2f(as1b[s3 * 8 + hh]);
            float p0 = __expf(lrelu(a0 + ad));
            float p1 = __expf(lrelu(a1 + ad));
            float p2 = __expf(lrelu(a2 + ad));
            float p3 = __expf(lrelu(a3 + ad));
            acc += p0 * h0 + p1 * h1v + p2 * h2v + p3 * h3;
            psum += (p0 + p1) + (p2 + p3);
        }
        for (; k < deg; ++k) {
            int s = readlane_i(sreg, k);
            float p = __expf(lrelu(b2f(as1b[s * 8 + hh]) + ad));
            acc += p * b2f(Hb[(size_t)s * 64 + lane]);
            psum += p;
        }
    } else {
        for (int k = 0; k < deg; ++k) {
            int s = __builtin_amdgcn_readfirstlane(csr[base + k]);
            float p = __expf(lrelu(b2f(as1b[s * 8 + hh]) + ad));
            acc += p * b2f(Hb[(size_t)s * 64 + lane]);
            psum += p;
        }
    }
    float v = acc / psum + b1[lane];
    h2[(size_t)n * 64 + lane] = v > 0.f ? v : __expf(v) - 1.f;  // ELU
}

// ---------------- GAT layer 2: bf16 gather, 1 head, bias; f32 output ----------------
__global__ __launch_bounds__(256) void gat2_kernel(
    const unsigned short* __restrict__ Zb, const unsigned short* __restrict__ as2b,
    const float* __restrict__ adn, const float* __restrict__ b2,
    const int* __restrict__ offv, const int* __restrict__ cnt,
    const int* __restrict__ csr, float* __restrict__ out, int N)
{
    int n = blockIdx.x * 4 + (threadIdx.x >> 6);
    if (n >= N) return;
    int lane = threadIdx.x & 63;
    int base = offv[n];
    int deg = cnt[n] + 1;
    float ad = adn[n];
    float acc = 0.f, psum = 0.f;

    if (deg <= 64) {
        int sreg = csr[base + (lane < deg ? lane : 0)];
        int k = 0;
        for (; k + 4 <= deg; k += 4) {
            int s0 = readlane_i(sreg, k), s1 = readlane_i(sreg, k + 1),
                s2 = readlane_i(sreg, k + 2), s3 = readlane_i(sreg, k + 3);
            float z0 = b2f(Zb[(size_t)s0 * 64 + lane]), a0 = b2f(as2b[s0]);
            float z1 = b2f(Zb[(size_t)s1 * 64 + lane]), a1 = b2f(as2b[s1]);
            float z2 = b2f(Zb[(size_t)s2 * 64 + lane]), a2 = b2f(as2b[s2]);
            float z3 = b2f(Zb[(size_t)s3 * 64 + lane]), a3 = b2f(as2b[s3]);
            float p0 = __expf(lrelu(a0 + ad));
            float p1 = __expf(lrelu(a1 + ad));
            float p2 = __expf(lrelu(a2 + ad));
            float p3 = __expf(lrelu(a3 + ad));
            acc += p0 * z0 + p1 * z1 + p2 * z2 + p3 * z3;
            psum += (p0 + p1) + (p2 + p3);
        }
        for (; k < deg; ++k) {
            int s = readlane_i(sreg, k);
            float p = __expf(lrelu(b2f(as2b[s]) + ad));
            acc += p * b2f(Zb[(size_t)s * 64 + lane]);
            psum += p;
        }
    } else {
        for (int k = 0; k < deg; ++k) {
            int s = __builtin_amdgcn_readfirstlane(csr[base + k]);
            float p = __expf(lrelu(b2f(as2b[s]) + ad));
            acc += p * b2f(Zb[(size_t)s * 64 + lane]);
            psum += p;
        }
    }
    out[(size_t)n * 64 + lane] = acc / psum + b2[lane];
}

// ---------------- decode: sigmoid(dot(z2[q0], z2[q1])) ----------------
__global__ __launch_bounds__(256) void decode_kernel(
    const float* __restrict__ z2, const int* __restrict__ q, int Q, float* __restrict__ out)
{
    int i = blockIdx.x * 4 + (threadIdx.x >> 6);
    if (i >= Q) return;
    int lane = threadIdx.x & 63;
    int a = q[i], b = q[Q + i];
    float v = z2[(size_t)a * 64 + lane] * z2[(size_t)b * 64 + lane];
#pragma unroll
    for (int d = 1; d < 64; d <<= 1) v += __shfl_xor(v, d);
    if (lane == 0) out[i] = 1.f / (1.f + __expf(-v));
}

extern "C" void kernel_launch(void* const* d_in, const int* in_sizes, int n_in,
                              void* d_out, int out_size, void* d_ws, size_t ws_size,
                              hipStream_t stream)
{
    const float* x   = (const float*)d_in[0];
    const int*   ei  = (const int*)d_in[1];
    const int*   qe  = (const int*)d_in[2];
    const float* W1  = (const float*)d_in[3];
    const float* as1 = (const float*)d_in[4];
    const float* ad1 = (const float*)d_in[5];
    const float* b1  = (const float*)d_in[6];
    const float* W2  = (const float*)d_in[7];
    const float* as2 = (const float*)d_in[8];
    const float* ad2 = (const float*)d_in[9];
    const float* b2  = (const float*)d_in[10];

    const int N = in_sizes[0] / 128;
    const int E = in_sizes[1] / 2;
    const int Q = in_sizes[2] / 2;

    float* out = (float*)d_out;

    // bucket sort params: 512-node buckets, 4096-edge tiles (NB,NT <= 256 req for LDS)
    int shift = 9;
    while ((((N + (1 << shift) - 1) >> shift)) > 256 && shift < 10) shift++;
    const int NB = (N + (1 << shift) - 1) >> shift;
    const int T  = 4096;
    const int NT = (E + T - 1) / T;

    char* ws = (char*)d_ws;
    size_t o = 0;
    auto alloc = [&](size_t bytes) -> void* {
        void* p = ws + o;
        o += (bytes + 255) & ~(size_t)255;
        return p;
    };
    unsigned short* hb   = (unsigned short*)alloc((size_t)N * 64 * 2); // h1 bf16, later z bf16
    float* f32buf        = (float*)alloc((size_t)N * 64 * 4);          // h2 f32, later z2 f32
    unsigned short* as1b = (unsigned short*)alloc((size_t)N * 8 * 2);
    float* adn1          = (float*)alloc((size_t)N * 8 * 4);
    unsigned short* as2b = (unsigned short*)alloc((size_t)N * 2);
    float* adn2          = (float*)alloc((size_t)N * 4);
    int*   cnt    = (int*)alloc((size_t)N * 4);
    int*   offv   = (int*)alloc((size_t)N * 4);
    int*   csr    = (int*)alloc((size_t)(E + N) * 4);
    int*   thist  = (int*)alloc((size_t)NT * NB * 4);
    int*   bbase  = (int*)alloc((size_t)(NB + 1) * 4);
    int2*  stg    = (int2*)alloc((size_t)E * 8);

    const int* esrc = ei;
    const int* edst = ei + E;

    int nodeBlocks4 = (N + 3) / 4;
    int tileBlocks  = (N + 63) / 64;

    gemm1_kernel<<<tileBlocks, 256, 0, stream>>>(x, W1, as1, ad1, hb, as1b, adn1, N);
    // CSR build: tile-stable bucket sort (no memsets; all state rebuilt per launch)
    bhist_kernel<<<NT, 256, 0, stream>>>(edst, E, T, shift, NB, thist);
    bscan_kernel<<<1, 256, 0, stream>>>(thist, NT, NB, bbase);
    bscatter_kernel<<<NT, 256, 0, stream>>>(esrc, edst, E, T, shift, NB, thist, stg);
    bbuild_kernel<<<NB, 256, 0, stream>>>(stg, bbase, shift, N, offv, cnt, csr);
    gat1_kernel<<<nodeBlocks4, 256, 0, stream>>>(hb, as1b, adn1, b1, offv, cnt, csr, f32buf, N);
    gemm2_kernel<<<tileBlocks, 256, 0, stream>>>(f32buf, W2, as2, ad2, hb, as2b, adn2, N);
    gat2_kernel<<<nodeBlocks4, 256, 0, stream>>>(hb, as2b, adn2, b2, offv, cnt, csr, f32buf, N);
    decode_kernel<<<(Q + 3) / 4, 256, 0, stream>>>(f32buf, qe, Q, out);
}

// Round 9
// 365.763 us; speedup vs baseline: 1.4359x; 1.2978x over previous
//
#include <hip/hip_runtime.h>
#include <math.h>

constexpr float NEG_SLOPE = 0.2f;

__device__ __forceinline__ float lrelu(float x) { return x > 0.f ? x : NEG_SLOPE * x; }

__device__ __forceinline__ int readlane_i(int v, int l) {
    return __builtin_amdgcn_readlane(v, l);
}
// bf16 pack (RNE) / unpack (exact)
__device__ __forceinline__ unsigned short f2b(float f) {
    unsigned u = __float_as_uint(f);
    unsigned r = u + 0x7FFFu + ((u >> 16) & 1u);
    return (unsigned short)(r >> 16);
}
__device__ __forceinline__ float b2f(unsigned short s) {
    return __uint_as_float((unsigned)s << 16);
}

#define MAC16(av, bv) \
    acc[0][0] += av.x*bv.x; acc[0][1] += av.x*bv.y; acc[0][2] += av.x*bv.z; acc[0][3] += av.x*bv.w; \
    acc[1][0] += av.y*bv.x; acc[1][1] += av.y*bv.y; acc[1][2] += av.y*bv.z; acc[1][3] += av.y*bv.w; \
    acc[2][0] += av.z*bv.x; acc[2][1] += av.z*bv.y; acc[2][2] += av.z*bv.z; acc[2][3] += av.z*bv.w; \
    acc[3][0] += av.w*bv.x; acc[3][1] += av.w*bv.y; acc[3][2] += av.w*bv.z; acc[3][3] += av.w*bv.w;

// ---------------- GEMM1: h1 = x @ W1 (64x64 tile, 4x4/thread) ----------------
__global__ __launch_bounds__(256) void gemm1_kernel(
    const float* __restrict__ X, const float* __restrict__ W,
    const float* __restrict__ a_s, const float* __restrict__ a_d,
    unsigned short* __restrict__ Hb, unsigned short* __restrict__ as1b,
    float* __restrict__ adn, int N)
{
    __shared__ float At[128 * 64];
    __shared__ float Bs[128 * 64];
    const int tid = threadIdx.x;
    const int r_base = blockIdx.x * 64;
    {
        const float4* W4 = (const float4*)W;
        float4* B4 = (float4*)Bs;
#pragma unroll
        for (int it = 0; it < 8; ++it) B4[tid + it * 256] = W4[tid + it * 256];
    }
    {
        const float4* X4 = (const float4*)X;
#pragma unroll
        for (int it = 0; it < 2; ++it) {
            int t = tid + it * 256;
            int rg = t & 15, cg = t >> 4;
            float4 rw[4];
#pragma unroll
            for (int j = 0; j < 4; ++j) {
                int r = r_base + rg * 4 + j;
                rw[j] = (r < N) ? X4[(size_t)r * 32 + cg] : make_float4(0.f, 0.f, 0.f, 0.f);
            }
            int rsw = 4 * (rg ^ (cg & 15));
            int k0 = cg * 4;
            *(float4*)&At[(k0    ) * 64 + rsw] = make_float4(rw[0].x, rw[1].x, rw[2].x, rw[3].x);
            *(float4*)&At[(k0 + 1) * 64 + rsw] = make_float4(rw[0].y, rw[1].y, rw[2].y, rw[3].y);
            *(float4*)&At[(k0 + 2) * 64 + rsw] = make_float4(rw[0].z, rw[1].z, rw[2].z, rw[3].z);
            *(float4*)&At[(k0 + 3) * 64 + rsw] = make_float4(rw[0].w, rw[1].w, rw[2].w, rw[3].w);
        }
    }
    __syncthreads();
    const int m  = tid & 15;
    const int ci = (tid >> 4) * 4;
    float acc[4][4] = {};
#pragma unroll 4
    for (int kq = 0; kq < 32; ++kq) {
        int aoff = kq * 256 + 4 * (m ^ (kq & 15));
        int boff = kq * 256 + ci;
        float4 a0 = *(const float4*)&At[aoff];
        float4 a1 = *(const float4*)&At[aoff + 64];
        float4 a2 = *(const float4*)&At[aoff + 128];
        float4 a3 = *(const float4*)&At[aoff + 192];
        float4 b0 = *(const float4*)&Bs[boff];
        float4 b1 = *(const float4*)&Bs[boff + 64];
        float4 b2 = *(const float4*)&Bs[boff + 128];
        float4 b3 = *(const float4*)&Bs[boff + 192];
        MAC16(a0, b0); MAC16(a1, b1); MAC16(a2, b2); MAC16(a3, b3);
    }
    float asv[4] = {a_s[ci], a_s[ci + 1], a_s[ci + 2], a_s[ci + 3]};
    float adv[4] = {a_d[ci], a_d[ci + 1], a_d[ci + 2], a_d[ci + 3]};
    int head = ci >> 3;
    bool owner = ((tid >> 4) & 1) == 0;
#pragma unroll
    for (int j = 0; j < 4; ++j) {
        int r = r_base + m * 4 + j;
        if (r < N) {
            ushort4 pk;
            pk.x = f2b(acc[j][0]); pk.y = f2b(acc[j][1]);
            pk.z = f2b(acc[j][2]); pk.w = f2b(acc[j][3]);
            *(ushort4*)&Hb[(size_t)r * 64 + ci] = pk;
        }
        float ps = acc[j][0]*asv[0] + acc[j][1]*asv[1] + acc[j][2]*asv[2] + acc[j][3]*asv[3];
        float pd = acc[j][0]*adv[0] + acc[j][1]*adv[1] + acc[j][2]*adv[2] + acc[j][3]*adv[3];
        ps += __shfl_xor(ps, 16);
        pd += __shfl_xor(pd, 16);
        if (owner && r < N) { as1b[r * 8 + head] = f2b(ps); adn[r * 8 + head] = pd; }
    }
}

// ---------------- GEMM2: z = h2 @ W2 (64x64 tile) ----------------
__global__ __launch_bounds__(256) void gemm2_kernel(
    const float* __restrict__ X, const float* __restrict__ W,
    const float* __restrict__ a_s, const float* __restrict__ a_d,
    unsigned short* __restrict__ Zb, unsigned short* __restrict__ as2b,
    float* __restrict__ adn, int N)
{
    __shared__ float At[64 * 64];
    __shared__ float Bs[64 * 64];
    __shared__ float Ps[4][16][4], Pd[4][16][4];
    const int tid = threadIdx.x;
    const int r_base = blockIdx.x * 64;
    {
        const float4* W4 = (const float4*)W;
        float4* B4 = (float4*)Bs;
#pragma unroll
        for (int it = 0; it < 4; ++it) B4[tid + it * 256] = W4[tid + it * 256];
    }
    {
        const float4* X4 = (const float4*)X;
        int rg = tid & 15, cg = tid >> 4;
        float4 rw[4];
#pragma unroll
        for (int j = 0; j < 4; ++j) {
            int r = r_base + rg * 4 + j;
            rw[j] = (r < N) ? X4[(size_t)r * 16 + cg] : make_float4(0.f, 0.f, 0.f, 0.f);
        }
        int rsw = 4 * (rg ^ (cg & 15));
        int k0 = cg * 4;
        *(float4*)&At[(k0    ) * 64 + rsw] = make_float4(rw[0].x, rw[1].x, rw[2].x, rw[3].x);
        *(float4*)&At[(k0 + 1) * 64 + rsw] = make_float4(rw[0].y, rw[1].y, rw[2].y, rw[3].y);
        *(float4*)&At[(k0 + 2) * 64 + rsw] = make_float4(rw[0].z, rw[1].z, rw[2].z, rw[3].z);
        *(float4*)&At[(k0 + 3) * 64 + rsw] = make_float4(rw[0].w, rw[1].w, rw[2].w, rw[3].w);
    }
    __syncthreads();
    const int m  = tid & 15;
    const int ci = (tid >> 4) * 4;
    float acc[4][4] = {};
#pragma unroll 4
    for (int kq = 0; kq < 16; ++kq) {
        int aoff = kq * 256 + 4 * (m ^ (kq & 15));
        int boff = kq * 256 + ci;
        float4 a0 = *(const float4*)&At[aoff];
        float4 a1 = *(const float4*)&At[aoff + 64];
        float4 a2 = *(const float4*)&At[aoff + 128];
        float4 a3 = *(const float4*)&At[aoff + 192];
        float4 b0 = *(const float4*)&Bs[boff];
        float4 b1 = *(const float4*)&Bs[boff + 64];
        float4 b2 = *(const float4*)&Bs[boff + 128];
        float4 b3 = *(const float4*)&Bs[boff + 192];
        MAC16(a0, b0); MAC16(a1, b1); MAC16(a2, b2); MAC16(a3, b3);
    }
    float asv[4] = {a_s[ci], a_s[ci + 1], a_s[ci + 2], a_s[ci + 3]};
    float adv[4] = {a_d[ci], a_d[ci + 1], a_d[ci + 2], a_d[ci + 3]};
    int w = tid >> 6;
    float ps[4], pd[4];
#pragma unroll
    for (int j = 0; j < 4; ++j) {
        int r = r_base + m * 4 + j;
        if (r < N) {
            ushort4 pk;
            pk.x = f2b(acc[j][0]); pk.y = f2b(acc[j][1]);
            pk.z = f2b(acc[j][2]); pk.w = f2b(acc[j][3]);
            *(ushort4*)&Zb[(size_t)r * 64 + ci] = pk;
        }
        ps[j] = acc[j][0]*asv[0] + acc[j][1]*asv[1] + acc[j][2]*asv[2] + acc[j][3]*asv[3];
        pd[j] = acc[j][0]*adv[0] + acc[j][1]*adv[1] + acc[j][2]*adv[2] + acc[j][3]*adv[3];
        ps[j] += __shfl_xor(ps[j], 16); ps[j] += __shfl_xor(ps[j], 32);
        pd[j] += __shfl_xor(pd[j], 16); pd[j] += __shfl_xor(pd[j], 32);
    }
    if (((tid >> 4) & 3) == 0) {
#pragma unroll
        for (int j = 0; j < 4; ++j) { Ps[w][m][j] = ps[j]; Pd[w][m][j] = pd[j]; }
    }
    __syncthreads();
    if (tid < 64) {
        int r = r_base + tid;
        if (r < N) {
            int mm = tid >> 2, jj = tid & 3;
            as2b[r] = f2b(Ps[0][mm][jj] + Ps[1][mm][jj] + Ps[2][mm][jj] + Ps[3][mm][jj]);
            adn[r]  = Pd[0][mm][jj] + Pd[1][mm][jj] + Pd[2][mm][jj] + Pd[3][mm][jj];
        }
    }
}

// ================= Tile-stable bucketed CSR build =================
// thist is BUCKET-MAJOR: thist[b*NT + t]. All outputs fully rewritten each
// launch by statically-assigned blocks; no cross-launch state, no memsets.

// S1: per-tile histogram (transposed stores)
__global__ __launch_bounds__(256) void bhist_kernel(
    const int* __restrict__ dst, int E, int T, int shift, int NB, int NT,
    int* __restrict__ thist)
{
    __shared__ int h[256];
    int t = blockIdx.x, tid = threadIdx.x;
    for (int i = tid; i < NB; i += 256) h[i] = 0;
    __syncthreads();
    int e0 = t * T, e1 = min(E, e0 + T);
    for (int e = e0 + tid; e < e1; e += 256) atomicAdd(&h[dst[e] >> shift], 1);
    __syncthreads();
    for (int i = tid; i < NB; i += 256) thist[(size_t)i * NT + t] = h[i];
}

// S2a: per-bucket total (one block per bucket, coalesced column reduce)
__global__ __launch_bounds__(256) void btot_kernel(
    const int* __restrict__ thist, int NT, int* __restrict__ btot)
{
    int b = blockIdx.x, tid = threadIdx.x;
    __shared__ int wsum[4];
    int s = 0;
    for (int t = tid; t < NT; t += 256) s += thist[(size_t)b * NT + t];
#pragma unroll
    for (int d = 1; d < 64; d <<= 1) s += __shfl_xor(s, d);
    if ((tid & 63) == 0) wsum[tid >> 6] = s;
    __syncthreads();
    if (tid == 0) btot[b] = wsum[0] + wsum[1] + wsum[2] + wsum[3];
}

// S2b: exclusive scan of bucket totals -> bbase[0..NB]
__global__ __launch_bounds__(64) void bbase_kernel(
    const int* __restrict__ btot, int NB, int* __restrict__ bbase)
{
    int lane = threadIdx.x;
    int carry = 0;
    for (int base = 0; base < NB; base += 64) {
        int i = base + lane;
        int v = (i < NB) ? btot[i] : 0;
        int incl = v;
#pragma unroll
        for (int d = 1; d < 64; d <<= 1) {
            int t = __shfl_up(incl, d);
            if (lane >= d) incl += t;
        }
        if (i < NB) bbase[i] = carry + incl - v;
        carry += __shfl(incl, 63);
    }
    if (lane == 0) bbase[NB] = carry;
}

// S2c: per-bucket exclusive scan of its tile column (+bbase), in place
__global__ __launch_bounds__(256) void bofs_kernel(
    int* __restrict__ thist, int NT, const int* __restrict__ bbase)
{
    int b = blockIdx.x, tid = threadIdx.x;
    int lane = tid & 63, w = tid >> 6;
    __shared__ int wsum[4];
    __shared__ int carry_s;
    if (tid == 0) carry_s = bbase[b];
    __syncthreads();
    for (int base = 0; base < NT; base += 256) {
        int t = base + tid;
        int v = (t < NT) ? thist[(size_t)b * NT + t] : 0;
        int incl = v;
#pragma unroll
        for (int d = 1; d < 64; d <<= 1) {
            int x = __shfl_up(incl, d);
            if (lane >= d) incl += x;
        }
        if (lane == 63) wsum[w] = incl;
        __syncthreads();
        int woff = 0;
        for (int i = 0; i < w; ++i) woff += wsum[i];
        if (t < NT) thist[(size_t)b * NT + t] = carry_s + woff + incl - v;
        __syncthreads();
        if (tid == 0) carry_s += wsum[0] + wsum[1] + wsum[2] + wsum[3];
        __syncthreads();
    }
}

// S3: scatter (src,dst) pairs into bucket-major staging
__global__ __launch_bounds__(256) void bscatter_kernel(
    const int* __restrict__ src, const int* __restrict__ dst, int E, int T,
    int shift, int NB, int NT, const int* __restrict__ thist, int2* __restrict__ stg)
{
    __shared__ int cur[256];
    int t = blockIdx.x, tid = threadIdx.x;
    for (int i = tid; i < NB; i += 256) cur[i] = thist[(size_t)i * NT + t];
    __syncthreads();
    int e0 = t * T, e1 = min(E, e0 + T);
    for (int e = e0 + tid; e < e1; e += 256) {
        int d = dst[e];
        int pos = atomicAdd(&cur[d >> shift], 1);
        stg[pos] = make_int2(src[e], d);
    }
}

// S4: per-bucket: counts -> scan -> offv/cnt/csr (self-loop at slot 0)
__global__ __launch_bounds__(256) void bbuild_kernel(
    const int2* __restrict__ stg, const int* __restrict__ bbase, int shift, int N,
    int* __restrict__ offv, int* __restrict__ cnt, int* __restrict__ csr)
{
    __shared__ int lcnt[1024], loff[1024], lfill[1024];
    int b = blockIdx.x, tid = threadIdx.x;
    int bs = 1 << shift;
    int n0 = b << shift;
    int e0 = bbase[b], e1 = bbase[b + 1];
    for (int i = tid; i < bs; i += 256) lcnt[i] = 0;
    __syncthreads();
    for (int e = e0 + tid; e < e1; e += 256) atomicAdd(&lcnt[stg[e].y - n0], 1);
    __syncthreads();
    if (tid < 64) {
        int seg = bs >> 6;
        int j0 = tid * seg;
        int local = 0;
        for (int j = 0; j < seg; ++j) {
            int n = n0 + j0 + j;
            local += (n < N) ? lcnt[j0 + j] + 1 : 0;
        }
        int incl = local;
#pragma unroll
        for (int d = 1; d < 64; d <<= 1) {
            int t2 = __shfl_up(incl, d);
            if (tid >= d) incl += t2;
        }
        int run = incl - local;
        for (int j = 0; j < seg; ++j) {
            int n = n0 + j0 + j;
            int v = (n < N) ? lcnt[j0 + j] + 1 : 0;
            loff[j0 + j] = run;
            run += v;
        }
    }
    __syncthreads();
    int csr_base = e0 + n0;   // edges before bucket + self-loops before bucket
    for (int i = tid; i < bs; i += 256) {
        int n = n0 + i;
        if (n < N) {
            int o = csr_base + loff[i];
            offv[n] = o;
            cnt[n] = lcnt[i];
            csr[o] = n;          // self loop at slot 0
            lfill[i] = loff[i] + 1;
        }
    }
    __syncthreads();
    for (int e = e0 + tid; e < e1; e += 256) {
        int2 p = stg[e];
        int pos = atomicAdd(&lfill[p.y - n0], 1);
        csr[csr_base + pos] = p.x;
    }
}

// ---------------- GAT layer 1: bf16 gather, fused single-pass, bias + ELU ----------------
__global__ __launch_bounds__(256) void gat1_kernel(
    const unsigned short* __restrict__ Hb, const unsigned short* __restrict__ as1b,
    const float* __restrict__ adn, const float* __restrict__ b1,
    const int* __restrict__ offv, const int* __restrict__ cnt,
    const int* __restrict__ csr, float* __restrict__ h2, int N)
{
    int n = blockIdx.x * 4 + (threadIdx.x >> 6);
    if (n >= N) return;
    int lane = threadIdx.x & 63;
    int base = offv[n];
    int deg = cnt[n] + 1;
    int hh = lane >> 3;
    float ad = adn[n * 8 + hh];
    float acc = 0.f, psum = 0.f;

    if (deg <= 64) {
        int sreg = csr[base + (lane < deg ? lane : 0)];
        int k = 0;
        for (; k + 4 <= deg; k += 4) {
            int s0 = readlane_i(sreg, k), s1 = readlane_i(sreg, k + 1),
                s2 = readlane_i(sreg, k + 2), s3 = readlane_i(sreg, k + 3);
            float h0 = b2f(Hb[(size_t)s0 * 64 + lane]), a0 = b2f(as1b[s0 * 8 + hh]);
            float h1v = b2f(Hb[(size_t)s1 * 64 + lane]), a1 = b2f(as1b[s1 * 8 + hh]);
            float h2v = b2f(Hb[(size_t)s2 * 64 + lane]), a2 = b2f(as1b[s2 * 8 + hh]);
            float h3 = b2f(Hb[(size_t)s3 * 64 + lane]), a3 = b2f(as1b[s3 * 8 + hh]);
            float p0 = __expf(lrelu(a0 + ad));
            float p1 = __expf(lrelu(a1 + ad));
            float p2 = __expf(lrelu(a2 + ad));
            float p3 = __expf(lrelu(a3 + ad));
            acc += p0 * h0 + p1 * h1v + p2 * h2v + p3 * h3;
            psum += (p0 + p1) + (p2 + p3);
        }
        for (; k < deg; ++k) {
            int s = readlane_i(sreg, k);
            float p = __expf(lrelu(b2f(as1b[s * 8 + hh]) + ad));
            acc += p * b2f(Hb[(size_t)s * 64 + lane]);
            psum += p;
        }
    } else {
        for (int k = 0; k < deg; ++k) {
            int s = __builtin_amdgcn_readfirstlane(csr[base + k]);
            float p = __expf(lrelu(b2f(as1b[s * 8 + hh]) + ad));
            acc += p * b2f(Hb[(size_t)s * 64 + lane]);
            psum += p;
        }
    }
    float v = acc / psum + b1[lane];
    h2[(size_t)n * 64 + lane] = v > 0.f ? v : __expf(v) - 1.f;  // ELU
}

// ---------------- GAT layer 2: bf16 gather, 1 head, bias; f32 output ----------------
__global__ __launch_bounds__(256) void gat2_kernel(
    const unsigned short* __restrict__ Zb, const unsigned short* __restrict__ as2b,
    const float* __restrict__ adn, const float* __restrict__ b2,
    const int* __restrict__ offv, const int* __restrict__ cnt,
    const int* __restrict__ csr, float* __restrict__ out, int N)
{
    int n = blockIdx.x * 4 + (threadIdx.x >> 6);
    if (n >= N) return;
    int lane = threadIdx.x & 63;
    int base = offv[n];
    int deg = cnt[n] + 1;
    float ad = adn[n];
    float acc = 0.f, psum = 0.f;

    if (deg <= 64) {
        int sreg = csr[base + (lane < deg ? lane : 0)];
        int k = 0;
        for (; k + 4 <= deg; k += 4) {
            int s0 = readlane_i(sreg, k), s1 = readlane_i(sreg, k + 1),
                s2 = readlane_i(sreg, k + 2), s3 = readlane_i(sreg, k + 3);
            float z0 = b2f(Zb[(size_t)s0 * 64 + lane]), a0 = b2f(as2b[s0]);
            float z1 = b2f(Zb[(size_t)s1 * 64 + lane]), a1 = b2f(as2b[s1]);
            float z2 = b2f(Zb[(size_t)s2 * 64 + lane]), a2 = b2f(as2b[s2]);
            float z3 = b2f(Zb[(size_t)s3 * 64 + lane]), a3 = b2f(as2b[s3]);
            float p0 = __expf(lrelu(a0 + ad));
            float p1 = __expf(lrelu(a1 + ad));
            float p2 = __expf(lrelu(a2 + ad));
            float p3 = __expf(lrelu(a3 + ad));
            acc += p0 * z0 + p1 * z1 + p2 * z2 + p3 * z3;
            psum += (p0 + p1) + (p2 + p3);
        }
        for (; k < deg; ++k) {
            int s = readlane_i(sreg, k);
            float p = __expf(lrelu(b2f(as2b[s]) + ad));
            acc += p * b2f(Zb[(size_t)s * 64 + lane]);
            psum += p;
        }
    } else {
        for (int k = 0; k < deg; ++k) {
            int s = __builtin_amdgcn_readfirstlane(csr[base + k]);
            float p = __expf(lrelu(b2f(as2b[s]) + ad));
            acc += p * b2f(Zb[(size_t)s * 64 + lane]);
            psum += p;
        }
    }
    out[(size_t)n * 64 + lane] = acc / psum + b2[lane];
}

// ---------------- decode: sigmoid(dot(z2[q0], z2[q1])) ----------------
__global__ __launch_bounds__(256) void decode_kernel(
    const float* __restrict__ z2, const int* __restrict__ q, int Q, float* __restrict__ out)
{
    int i = blockIdx.x * 4 + (threadIdx.x >> 6);
    if (i >= Q) return;
    int lane = threadIdx.x & 63;
    int a = q[i], b = q[Q + i];
    float v = z2[(size_t)a * 64 + lane] * z2[(size_t)b * 64 + lane];
#pragma unroll
    for (int d = 1; d < 64; d <<= 1) v += __shfl_xor(v, d);
    if (lane == 0) out[i] = 1.f / (1.f + __expf(-v));
}

extern "C" void kernel_launch(void* const* d_in, const int* in_sizes, int n_in,
                              void* d_out, int out_size, void* d_ws, size_t ws_size,
                              hipStream_t stream)
{
    const float* x   = (const float*)d_in[0];
    const int*   ei  = (const int*)d_in[1];
    const int*   qe  = (const int*)d_in[2];
    const float* W1  = (const float*)d_in[3];
    const float* as1 = (const float*)d_in[4];
    const float* ad1 = (const float*)d_in[5];
    const float* b1  = (const float*)d_in[6];
    const float* W2  = (const float*)d_in[7];
    const float* as2 = (const float*)d_in[8];
    const float* ad2 = (const float*)d_in[9];
    const float* b2  = (const float*)d_in[10];

    const int N = in_sizes[0] / 128;
    const int E = in_sizes[1] / 2;
    const int Q = in_sizes[2] / 2;

    float* out = (float*)d_out;

    // bucket sort params: 512-node buckets, 4096-edge tiles (NB <= 256 for LDS)
    int shift = 9;
    while ((((N + (1 << shift) - 1) >> shift)) > 256 && shift < 10) shift++;
    const int NB = (N + (1 << shift) - 1) >> shift;
    const int T  = 4096;
    const int NT = (E + T - 1) / T;

    char* ws = (char*)d_ws;
    size_t o = 0;
    auto alloc = [&](size_t bytes) -> void* {
        void* p = ws + o;
        o += (bytes + 255) & ~(size_t)255;
        return p;
    };
    unsigned short* hb   = (unsigned short*)alloc((size_t)N * 64 * 2); // h1 bf16, later z bf16
    float* f32buf        = (float*)alloc((size_t)N * 64 * 4);          // h2 f32, later z2 f32
    unsigned short* as1b = (unsigned short*)alloc((size_t)N * 8 * 2);
    float* adn1          = (float*)alloc((size_t)N * 8 * 4);
    unsigned short* as2b = (unsigned short*)alloc((size_t)N * 2);
    float* adn2          = (float*)alloc((size_t)N * 4);
    int*   cnt    = (int*)alloc((size_t)N * 4);
    int*   offv   = (int*)alloc((size_t)N * 4);
    int*   csr    = (int*)alloc((size_t)(E + N) * 4);
    int*   thist  = (int*)alloc((size_t)NB * NT * 4);   // bucket-major [b][t]
    int*   btot   = (int*)alloc((size_t)NB * 4);
    int*   bbase  = (int*)alloc((size_t)(NB + 1) * 4);
    int2*  stg    = (int2*)alloc((size_t)E * 8);

    const int* esrc = ei;
    const int* edst = ei + E;

    int nodeBlocks4 = (N + 3) / 4;
    int tileBlocks  = (N + 63) / 64;

    gemm1_kernel<<<tileBlocks, 256, 0, stream>>>(x, W1, as1, ad1, hb, as1b, adn1, N);
    // CSR build: tile-stable bucket sort with parallel hierarchical scan
    bhist_kernel<<<NT, 256, 0, stream>>>(edst, E, T, shift, NB, NT, thist);
    btot_kernel<<<NB, 256, 0, stream>>>(thist, NT, btot);
    bbase_kernel<<<1, 64, 0, stream>>>(btot, NB, bbase);
    bofs_kernel<<<NB, 256, 0, stream>>>(thist, NT, bbase);
    bscatter_kernel<<<NT, 256, 0, stream>>>(esrc, edst, E, T, shift, NB, NT, thist, stg);
    bbuild_kernel<<<NB, 256, 0, stream>>>(stg, bbase, shift, N, offv, cnt, csr);
    gat1_kernel<<<nodeBlocks4, 256, 0, stream>>>(hb, as1b, adn1, b1, offv, cnt, csr, f32buf, N);
    gemm2_kernel<<<tileBlocks, 256, 0, stream>>>(f32buf, W2, as2, ad2, hb, as2b, adn2, N);
    gat2_kernel<<<nodeBlocks4, 256, 0, stream>>>(hb, as2b, adn2, b2, offv, cnt, csr, f32buf, N);
    decode_kernel<<<(Q + 3) / 4, 256, 0, stream>>>(f32buf, qe, Q, out);
}

// Round 10
// 350.670 us; speedup vs baseline: 1.4977x; 1.0430x over previous
//
#include <hip/hip_runtime.h>
#include <math.h>

constexpr float NEG_SLOPE = 0.2f;

__device__ __forceinline__ float lrelu(float x) { return x > 0.f ? x : NEG_SLOPE * x; }

__device__ __forceinline__ int readlane_i(int v, int l) {
    return __builtin_amdgcn_readlane(v, l);
}
__device__ __forceinline__ float readlane_f(float v, int l) {
    return __uint_as_float(__builtin_amdgcn_readlane(__float_as_uint(v), l));
}
// bf16 pack (RNE) / unpack (exact)
__device__ __forceinline__ unsigned short f2b(float f) {
    unsigned u = __float_as_uint(f);
    unsigned r = u + 0x7FFFu + ((u >> 16) & 1u);
    return (unsigned short)(r >> 16);
}
__device__ __forceinline__ float b2f(unsigned short s) {
    return __uint_as_float((unsigned)s << 16);
}

#define MAC16(av, bv) \
    acc[0][0] += av.x*bv.x; acc[0][1] += av.x*bv.y; acc[0][2] += av.x*bv.z; acc[0][3] += av.x*bv.w; \
    acc[1][0] += av.y*bv.x; acc[1][1] += av.y*bv.y; acc[1][2] += av.y*bv.z; acc[1][3] += av.y*bv.w; \
    acc[2][0] += av.z*bv.x; acc[2][1] += av.z*bv.y; acc[2][2] += av.z*bv.z; acc[2][3] += av.z*bv.w; \
    acc[3][0] += av.w*bv.x; acc[3][1] += av.w*bv.y; acc[3][2] += av.w*bv.z; acc[3][3] += av.w*bv.w;

// ---------------- GEMM1: h1 = x @ W1 (64x64 tile, 4x4/thread) ----------------
__global__ __launch_bounds__(256) void gemm1_kernel(
    const float* __restrict__ X, const float* __restrict__ W,
    const float* __restrict__ a_s, const float* __restrict__ a_d,
    unsigned short* __restrict__ Hb, unsigned short* __restrict__ as1b,
    float* __restrict__ adn, int N)
{
    __shared__ float At[128 * 64];
    __shared__ float Bs[128 * 64];
    const int tid = threadIdx.x;
    const int r_base = blockIdx.x * 64;
    {
        const float4* W4 = (const float4*)W;
        float4* B4 = (float4*)Bs;
#pragma unroll
        for (int it = 0; it < 8; ++it) B4[tid + it * 256] = W4[tid + it * 256];
    }
    {
        const float4* X4 = (const float4*)X;
#pragma unroll
        for (int it = 0; it < 2; ++it) {
            int t = tid + it * 256;
            int rg = t & 15, cg = t >> 4;
            float4 rw[4];
#pragma unroll
            for (int j = 0; j < 4; ++j) {
                int r = r_base + rg * 4 + j;
                rw[j] = (r < N) ? X4[(size_t)r * 32 + cg] : make_float4(0.f, 0.f, 0.f, 0.f);
            }
            int rsw = 4 * (rg ^ (cg & 15));
            int k0 = cg * 4;
            *(float4*)&At[(k0    ) * 64 + rsw] = make_float4(rw[0].x, rw[1].x, rw[2].x, rw[3].x);
            *(float4*)&At[(k0 + 1) * 64 + rsw] = make_float4(rw[0].y, rw[1].y, rw[2].y, rw[3].y);
            *(float4*)&At[(k0 + 2) * 64 + rsw] = make_float4(rw[0].z, rw[1].z, rw[2].z, rw[3].z);
            *(float4*)&At[(k0 + 3) * 64 + rsw] = make_float4(rw[0].w, rw[1].w, rw[2].w, rw[3].w);
        }
    }
    __syncthreads();
    const int m  = tid & 15;
    const int ci = (tid >> 4) * 4;
    float acc[4][4] = {};
#pragma unroll 4
    for (int kq = 0; kq < 32; ++kq) {
        int aoff = kq * 256 + 4 * (m ^ (kq & 15));
        int boff = kq * 256 + ci;
        float4 a0 = *(const float4*)&At[aoff];
        float4 a1 = *(const float4*)&At[aoff + 64];
        float4 a2 = *(const float4*)&At[aoff + 128];
        float4 a3 = *(const float4*)&At[aoff + 192];
        float4 b0 = *(const float4*)&Bs[boff];
        float4 b1 = *(const float4*)&Bs[boff + 64];
        float4 b2 = *(const float4*)&Bs[boff + 128];
        float4 b3 = *(const float4*)&Bs[boff + 192];
        MAC16(a0, b0); MAC16(a1, b1); MAC16(a2, b2); MAC16(a3, b3);
    }
    float asv[4] = {a_s[ci], a_s[ci + 1], a_s[ci + 2], a_s[ci + 3]};
    float adv[4] = {a_d[ci], a_d[ci + 1], a_d[ci + 2], a_d[ci + 3]};
    int head = ci >> 3;
    bool owner = ((tid >> 4) & 1) == 0;
#pragma unroll
    for (int j = 0; j < 4; ++j) {
        int r = r_base + m * 4 + j;
        if (r < N) {
            ushort4 pk;
            pk.x = f2b(acc[j][0]); pk.y = f2b(acc[j][1]);
            pk.z = f2b(acc[j][2]); pk.w = f2b(acc[j][3]);
            *(ushort4*)&Hb[(size_t)r * 64 + ci] = pk;
        }
        float ps = acc[j][0]*asv[0] + acc[j][1]*asv[1] + acc[j][2]*asv[2] + acc[j][3]*asv[3];
        float pd = acc[j][0]*adv[0] + acc[j][1]*adv[1] + acc[j][2]*adv[2] + acc[j][3]*adv[3];
        ps += __shfl_xor(ps, 16);
        pd += __shfl_xor(pd, 16);
        if (owner && r < N) { as1b[r * 8 + head] = f2b(ps); adn[r * 8 + head] = pd; }
    }
}

// ---------------- GEMM2: z = h2 @ W2 (64x64 tile) ----------------
__global__ __launch_bounds__(256) void gemm2_kernel(
    const float* __restrict__ X, const float* __restrict__ W,
    const float* __restrict__ a_s, const float* __restrict__ a_d,
    unsigned short* __restrict__ Zb, unsigned short* __restrict__ as2b,
    float* __restrict__ adn, int N)
{
    __shared__ float At[64 * 64];
    __shared__ float Bs[64 * 64];
    __shared__ float Ps[4][16][4], Pd[4][16][4];
    const int tid = threadIdx.x;
    const int r_base = blockIdx.x * 64;
    {
        const float4* W4 = (const float4*)W;
        float4* B4 = (float4*)Bs;
#pragma unroll
        for (int it = 0; it < 4; ++it) B4[tid + it * 256] = W4[tid + it * 256];
    }
    {
        const float4* X4 = (const float4*)X;
        int rg = tid & 15, cg = tid >> 4;
        float4 rw[4];
#pragma unroll
        for (int j = 0; j < 4; ++j) {
            int r = r_base + rg * 4 + j;
            rw[j] = (r < N) ? X4[(size_t)r * 16 + cg] : make_float4(0.f, 0.f, 0.f, 0.f);
        }
        int rsw = 4 * (rg ^ (cg & 15));
        int k0 = cg * 4;
        *(float4*)&At[(k0    ) * 64 + rsw] = make_float4(rw[0].x, rw[1].x, rw[2].x, rw[3].x);
        *(float4*)&At[(k0 + 1) * 64 + rsw] = make_float4(rw[0].y, rw[1].y, rw[2].y, rw[3].y);
        *(float4*)&At[(k0 + 2) * 64 + rsw] = make_float4(rw[0].z, rw[1].z, rw[2].z, rw[3].z);
        *(float4*)&At[(k0 + 3) * 64 + rsw] = make_float4(rw[0].w, rw[1].w, rw[2].w, rw[3].w);
    }
    __syncthreads();
    const int m  = tid & 15;
    const int ci = (tid >> 4) * 4;
    float acc[4][4] = {};
#pragma unroll 4
    for (int kq = 0; kq < 16; ++kq) {
        int aoff = kq * 256 + 4 * (m ^ (kq & 15));
        int boff = kq * 256 + ci;
        float4 a0 = *(const float4*)&At[aoff];
        float4 a1 = *(const float4*)&At[aoff + 64];
        float4 a2 = *(const float4*)&At[aoff + 128];
        float4 a3 = *(const float4*)&At[aoff + 192];
        float4 b0 = *(const float4*)&Bs[boff];
        float4 b1 = *(const float4*)&Bs[boff + 64];
        float4 b2 = *(const float4*)&Bs[boff + 128];
        float4 b3 = *(const float4*)&Bs[boff + 192];
        MAC16(a0, b0); MAC16(a1, b1); MAC16(a2, b2); MAC16(a3, b3);
    }
    float asv[4] = {a_s[ci], a_s[ci + 1], a_s[ci + 2], a_s[ci + 3]};
    float adv[4] = {a_d[ci], a_d[ci + 1], a_d[ci + 2], a_d[ci + 3]};
    int w = tid >> 6;
    float ps[4], pd[4];
#pragma unroll
    for (int j = 0; j < 4; ++j) {
        int r = r_base + m * 4 + j;
        if (r < N) {
            ushort4 pk;
            pk.x = f2b(acc[j][0]); pk.y = f2b(acc[j][1]);
            pk.z = f2b(acc[j][2]); pk.w = f2b(acc[j][3]);
            *(ushort4*)&Zb[(size_t)r * 64 + ci] = pk;
        }
        ps[j] = acc[j][0]*asv[0] + acc[j][1]*asv[1] + acc[j][2]*asv[2] + acc[j][3]*asv[3];
        pd[j] = acc[j][0]*adv[0] + acc[j][1]*adv[1] + acc[j][2]*adv[2] + acc[j][3]*adv[3];
        ps[j] += __shfl_xor(ps[j], 16); ps[j] += __shfl_xor(ps[j], 32);
        pd[j] += __shfl_xor(pd[j], 16); pd[j] += __shfl_xor(pd[j], 32);
    }
    if (((tid >> 4) & 3) == 0) {
#pragma unroll
        for (int j = 0; j < 4; ++j) { Ps[w][m][j] = ps[j]; Pd[w][m][j] = pd[j]; }
    }
    __syncthreads();
    if (tid < 64) {
        int r = r_base + tid;
        if (r < N) {
            int mm = tid >> 2, jj = tid & 3;
            as2b[r] = f2b(Ps[0][mm][jj] + Ps[1][mm][jj] + Ps[2][mm][jj] + Ps[3][mm][jj]);
            adn[r]  = Pd[0][mm][jj] + Pd[1][mm][jj] + Pd[2][mm][jj] + Pd[3][mm][jj];
        }
    }
}

// ================= Tile-stable bucketed CSR build (proven replay-safe) =================
__global__ __launch_bounds__(256) void bhist_kernel(
    const int* __restrict__ dst, int E, int T, int shift, int NB, int NT,
    int* __restrict__ thist)
{
    __shared__ int h[256];
    int t = blockIdx.x, tid = threadIdx.x;
    for (int i = tid; i < NB; i += 256) h[i] = 0;
    __syncthreads();
    int e0 = t * T, e1 = min(E, e0 + T);
    for (int e = e0 + tid; e < e1; e += 256) atomicAdd(&h[dst[e] >> shift], 1);
    __syncthreads();
    for (int i = tid; i < NB; i += 256) thist[(size_t)i * NT + t] = h[i];
}

__global__ __launch_bounds__(256) void btot_kernel(
    const int* __restrict__ thist, int NT, int* __restrict__ btot)
{
    int b = blockIdx.x, tid = threadIdx.x;
    __shared__ int wsum[4];
    int s = 0;
    for (int t = tid; t < NT; t += 256) s += thist[(size_t)b * NT + t];
#pragma unroll
    for (int d = 1; d < 64; d <<= 1) s += __shfl_xor(s, d);
    if ((tid & 63) == 0) wsum[tid >> 6] = s;
    __syncthreads();
    if (tid == 0) btot[b] = wsum[0] + wsum[1] + wsum[2] + wsum[3];
}

__global__ __launch_bounds__(64) void bbase_kernel(
    const int* __restrict__ btot, int NB, int* __restrict__ bbase)
{
    int lane = threadIdx.x;
    int carry = 0;
    for (int base = 0; base < NB; base += 64) {
        int i = base + lane;
        int v = (i < NB) ? btot[i] : 0;
        int incl = v;
#pragma unroll
        for (int d = 1; d < 64; d <<= 1) {
            int t = __shfl_up(incl, d);
            if (lane >= d) incl += t;
        }
        if (i < NB) bbase[i] = carry + incl - v;
        carry += __shfl(incl, 63);
    }
    if (lane == 0) bbase[NB] = carry;
}

__global__ __launch_bounds__(256) void bofs_kernel(
    int* __restrict__ thist, int NT, const int* __restrict__ bbase)
{
    int b = blockIdx.x, tid = threadIdx.x;
    int lane = tid & 63, w = tid >> 6;
    __shared__ int wsum[4];
    __shared__ int carry_s;
    if (tid == 0) carry_s = bbase[b];
    __syncthreads();
    for (int base = 0; base < NT; base += 256) {
        int t = base + tid;
        int v = (t < NT) ? thist[(size_t)b * NT + t] : 0;
        int incl = v;
#pragma unroll
        for (int d = 1; d < 64; d <<= 1) {
            int x = __shfl_up(incl, d);
            if (lane >= d) incl += x;
        }
        if (lane == 63) wsum[w] = incl;
        __syncthreads();
        int woff = 0;
        for (int i = 0; i < w; ++i) woff += wsum[i];
        if (t < NT) thist[(size_t)b * NT + t] = carry_s + woff + incl - v;
        __syncthreads();
        if (tid == 0) carry_s += wsum[0] + wsum[1] + wsum[2] + wsum[3];
        __syncthreads();
    }
}

__global__ __launch_bounds__(256) void bscatter_kernel(
    const int* __restrict__ src, const int* __restrict__ dst, int E, int T,
    int shift, int NB, int NT, const int* __restrict__ thist, int2* __restrict__ stg)
{
    __shared__ int cur[256];
    int t = blockIdx.x, tid = threadIdx.x;
    for (int i = tid; i < NB; i += 256) cur[i] = thist[(size_t)i * NT + t];
    __syncthreads();
    int e0 = t * T, e1 = min(E, e0 + T);
    for (int e = e0 + tid; e < e1; e += 256) {
        int d = dst[e];
        int pos = atomicAdd(&cur[d >> shift], 1);
        stg[pos] = make_int2(src[e], d);
    }
}

__global__ __launch_bounds__(256) void bbuild_kernel(
    const int2* __restrict__ stg, const int* __restrict__ bbase, int shift, int N,
    int* __restrict__ offv, int* __restrict__ cnt, int* __restrict__ csr)
{
    __shared__ int lcnt[1024], loff[1024], lfill[1024];
    int b = blockIdx.x, tid = threadIdx.x;
    int bs = 1 << shift;
    int n0 = b << shift;
    int e0 = bbase[b], e1 = bbase[b + 1];
    for (int i = tid; i < bs; i += 256) lcnt[i] = 0;
    __syncthreads();
    for (int e = e0 + tid; e < e1; e += 256) atomicAdd(&lcnt[stg[e].y - n0], 1);
    __syncthreads();
    if (tid < 64) {
        int seg = bs >> 6;
        int j0 = tid * seg;
        int local = 0;
        for (int j = 0; j < seg; ++j) {
            int n = n0 + j0 + j;
            local += (n < N) ? lcnt[j0 + j] + 1 : 0;
        }
        int incl = local;
#pragma unroll
        for (int d = 1; d < 64; d <<= 1) {
            int t2 = __shfl_up(incl, d);
            if (tid >= d) incl += t2;
        }
        int run = incl - local;
        for (int j = 0; j < seg; ++j) {
            int n = n0 + j0 + j;
            int v = (n < N) ? lcnt[j0 + j] + 1 : 0;
            loff[j0 + j] = run;
            run += v;
        }
    }
    __syncthreads();
    int csr_base = e0 + n0;
    for (int i = tid; i < bs; i += 256) {
        int n = n0 + i;
        if (n < N) {
            int o = csr_base + loff[i];
            offv[n] = o;
            cnt[n] = lcnt[i];
            csr[o] = n;          // self loop at slot 0
            lfill[i] = loff[i] + 1;
        }
    }
    __syncthreads();
    for (int e = e0 + tid; e < e1; e += 256) {
        int2 p = stg[e];
        int pos = atomicAdd(&lfill[p.y - n0], 1);
        csr[csr_base + pos] = p.x;
    }
}

// ---------------- GAT layer 1: distributed-p (edge x head lanes), bf16 gather ----------------
__global__ __launch_bounds__(256) void gat1_kernel(
    const unsigned short* __restrict__ Hb, const unsigned short* __restrict__ as1b,
    const float* __restrict__ adn, const float* __restrict__ b1,
    const int* __restrict__ offv, const int* __restrict__ cnt,
    const int* __restrict__ csr, float* __restrict__ h2, int N)
{
    int n = blockIdx.x * 4 + (threadIdx.x >> 6);
    if (n >= N) return;
    int lane = threadIdx.x & 63;
    int base = offv[n];
    int deg = cnt[n] + 1;
    int hh = lane >> 3;                 // accumulation head (column group)
    int jC = lane >> 3, hC = lane & 7;  // compute layout: edge-slot jC, head hC
    float adC = adn[n * 8 + hC];
    float acc = 0.f, psum = 0.f;

    if (deg <= 64) {
        int sreg = csr[base + (lane < deg ? lane : 0)];
        int c0 = 0;
        for (; c0 + 8 <= deg; c0 += 8) {
            // one alpha load + one exp per lane serves 8 edges x 8 heads
            int sj = __shfl(sreg, c0 + jC);
            float p = __expf(lrelu(b2f(as1b[sj * 8 + hC]) + adC));
#pragma unroll
            for (int jj = 0; jj < 8; ++jj) {
                float pj = __shfl(p, jj * 8 + hh);
                int s = readlane_i(sreg, c0 + jj);
                acc += pj * b2f(Hb[(size_t)s * 64 + lane]);
                psum += pj;
            }
        }
        if (c0 < deg) {
            int idx = c0 + jC;                  // <= 63 always
            int sj = __shfl(sreg, idx);
            float p = (idx < deg) ? __expf(lrelu(b2f(as1b[sj * 8 + hC]) + adC)) : 0.f;
            int rem = deg - c0;
            for (int jj = 0; jj < rem; ++jj) {
                float pj = __shfl(p, jj * 8 + hh);
                int s = readlane_i(sreg, c0 + jj);
                acc += pj * b2f(Hb[(size_t)s * 64 + lane]);
                psum += pj;
            }
        }
    } else {
        // fallback (deg > 64): per-edge recompute
        float ad = adn[n * 8 + hh];
        for (int k = 0; k < deg; ++k) {
            int s = __builtin_amdgcn_readfirstlane(csr[base + k]);
            float p = __expf(lrelu(b2f(as1b[s * 8 + hh]) + ad));
            acc += p * b2f(Hb[(size_t)s * 64 + lane]);
            psum += p;
        }
    }
    float v = acc / psum + b1[lane];
    h2[(size_t)n * 64 + lane] = v > 0.f ? v : __expf(v) - 1.f;  // ELU
}

// ---------------- GAT layer 2: vectorized-p (one exp per edge, total), bf16 gather ----------------
__global__ __launch_bounds__(256) void gat2_kernel(
    const unsigned short* __restrict__ Zb, const unsigned short* __restrict__ as2b,
    const float* __restrict__ adn, const float* __restrict__ b2,
    const int* __restrict__ offv, const int* __restrict__ cnt,
    const int* __restrict__ csr, float* __restrict__ out, int N)
{
    int n = blockIdx.x * 4 + (threadIdx.x >> 6);
    if (n >= N) return;
    int lane = threadIdx.x & 63;
    int base = offv[n];
    int deg = cnt[n] + 1;
    float ad = adn[n];
    float acc = 0.f, psum;

    if (deg <= 64) {
        int sreg = csr[base + (lane < deg ? lane : 0)];
        float aE = b2f(as2b[sreg]);                      // own edge's alpha
        float p = (lane < deg) ? __expf(lrelu(aE + ad)) : 0.f;
        psum = p;
#pragma unroll
        for (int d = 1; d < 64; d <<= 1) psum += __shfl_xor(psum, d);
        int k = 0;
        for (; k + 4 <= deg; k += 4) {
            int s0 = readlane_i(sreg, k), s1 = readlane_i(sreg, k + 1),
                s2 = readlane_i(sreg, k + 2), s3 = readlane_i(sreg, k + 3);
            float p0 = readlane_f(p, k), p1 = readlane_f(p, k + 1),
                  p2 = readlane_f(p, k + 2), p3 = readlane_f(p, k + 3);
            acc += p0 * b2f(Zb[(size_t)s0 * 64 + lane]);
            acc += p1 * b2f(Zb[(size_t)s1 * 64 + lane]);
            acc += p2 * b2f(Zb[(size_t)s2 * 64 + lane]);
            acc += p3 * b2f(Zb[(size_t)s3 * 64 + lane]);
        }
        for (; k < deg; ++k)
            acc += readlane_f(p, k) * b2f(Zb[(size_t)readlane_i(sreg, k) * 64 + lane]);
    } else {
        psum = 0.f;
        for (int k = 0; k < deg; ++k) {
            int s = __builtin_amdgcn_readfirstlane(csr[base + k]);
            float p = __expf(lrelu(b2f(as2b[s]) + ad));
            acc += p * b2f(Zb[(size_t)s * 64 + lane]);
            psum += p;
        }
    }
    out[(size_t)n * 64 + lane] = acc / psum + b2[lane];
}

// ---------------- decode: sigmoid(dot(z2[q0], z2[q1])) ----------------
__global__ __launch_bounds__(256) void decode_kernel(
    const float* __restrict__ z2, const int* __restrict__ q, int Q, float* __restrict__ out)
{
    int i = blockIdx.x * 4 + (threadIdx.x >> 6);
    if (i >= Q) return;
    int lane = threadIdx.x & 63;
    int a = q[i], b = q[Q + i];
    float v = z2[(size_t)a * 64 + lane] * z2[(size_t)b * 64 + lane];
#pragma unroll
    for (int d = 1; d < 64; d <<= 1) v += __shfl_xor(v, d);
    if (lane == 0) out[i] = 1.f / (1.f + __expf(-v));
}

extern "C" void kernel_launch(void* const* d_in, const int* in_sizes, int n_in,
                              void* d_out, int out_size, void* d_ws, size_t ws_size,
                              hipStream_t stream)
{
    const float* x   = (const float*)d_in[0];
    const int*   ei  = (const int*)d_in[1];
    const int*   qe  = (const int*)d_in[2];
    const float* W1  = (const float*)d_in[3];
    const float* as1 = (const float*)d_in[4];
    const float* ad1 = (const float*)d_in[5];
    const float* b1  = (const float*)d_in[6];
    const float* W2  = (const float*)d_in[7];
    const float* as2 = (const float*)d_in[8];
    const float* ad2 = (const float*)d_in[9];
    const float* b2  = (const float*)d_in[10];

    const int N = in_sizes[0] / 128;
    const int E = in_sizes[1] / 2;
    const int Q = in_sizes[2] / 2;

    float* out = (float*)d_out;

    int shift = 9;
    while ((((N + (1 << shift) - 1) >> shift)) > 256 && shift < 10) shift++;
    const int NB = (N + (1 << shift) - 1) >> shift;
    const int T  = 4096;
    const int NT = (E + T - 1) / T;

    char* ws = (char*)d_ws;
    size_t o = 0;
    auto alloc = [&](size_t bytes) -> void* {
        void* p = ws + o;
        o += (bytes + 255) & ~(size_t)255;
        return p;
    };
    unsigned short* hb   = (unsigned short*)alloc((size_t)N * 64 * 2); // h1 bf16, later z bf16
    float* f32buf        = (float*)alloc((size_t)N * 64 * 4);          // h2 f32, later z2 f32
    unsigned short* as1b = (unsigned short*)alloc((size_t)N * 8 * 2);
    float* adn1          = (float*)alloc((size_t)N * 8 * 4);
    unsigned short* as2b = (unsigned short*)alloc((size_t)N * 2);
    float* adn2          = (float*)alloc((size_t)N * 4);
    int*   cnt    = (int*)alloc((size_t)N * 4);
    int*   offv   = (int*)alloc((size_t)N * 4);
    int*   csr    = (int*)alloc((size_t)(E + N) * 4);
    int*   thist  = (int*)alloc((size_t)NB * NT * 4);   // bucket-major [b][t]
    int*   btot   = (int*)alloc((size_t)NB * 4);
    int*   bbase  = (int*)alloc((size_t)(NB + 1) * 4);
    int2*  stg    = (int2*)alloc((size_t)E * 8);

    const int* esrc = ei;
    const int* edst = ei + E;

    int nodeBlocks4 = (N + 3) / 4;
    int tileBlocks  = (N + 63) / 64;

    gemm1_kernel<<<tileBlocks, 256, 0, stream>>>(x, W1, as1, ad1, hb, as1b, adn1, N);
    bhist_kernel<<<NT, 256, 0, stream>>>(edst, E, T, shift, NB, NT, thist);
    btot_kernel<<<NB, 256, 0, stream>>>(thist, NT, btot);
    bbase_kernel<<<1, 64, 0, stream>>>(btot, NB, bbase);
    bofs_kernel<<<NB, 256, 0, stream>>>(thist, NT, bbase);
    bscatter_kernel<<<NT, 256, 0, stream>>>(esrc, edst, E, T, shift, NB, NT, thist, stg);
    bbuild_kernel<<<NB, 256, 0, stream>>>(stg, bbase, shift, N, offv, cnt, csr);
    gat1_kernel<<<nodeBlocks4, 256, 0, stream>>>(hb, as1b, adn1, b1, offv, cnt, csr, f32buf, N);
    gemm2_kernel<<<tileBlocks, 256, 0, stream>>>(f32buf, W2, as2, ad2, hb, as2b, adn2, N);
    gat2_kernel<<<nodeBlocks4, 256, 0, stream>>>(hb, as2b, adn2, b2, offv, cnt, csr, f32buf, N);
    decode_kernel<<<(Q + 3) / 4, 256, 0, stream>>>(f32buf, qe, Q, out);
}

// Round 11
// 330.305 us; speedup vs baseline: 1.5900x; 1.0617x over previous
//
#include <hip/hip_runtime.h>
#include <math.h>

constexpr float NEG_SLOPE = 0.2f;

__device__ __forceinline__ float lrelu(float x) { return x > 0.f ? x : NEG_SLOPE * x; }

__device__ __forceinline__ int readlane_i(int v, int l) {
    return __builtin_amdgcn_readlane(v, l);
}
// bf16 pack (RNE) / unpack (exact)
__device__ __forceinline__ unsigned short f2b(float f) {
    unsigned u = __float_as_uint(f);
    unsigned r = u + 0x7FFFu + ((u >> 16) & 1u);
    return (unsigned short)(r >> 16);
}
__device__ __forceinline__ float b2f(unsigned short s) {
    return __uint_as_float((unsigned)s << 16);
}

#define MAC16(av, bv) \
    acc[0][0] += av.x*bv.x; acc[0][1] += av.x*bv.y; acc[0][2] += av.x*bv.z; acc[0][3] += av.x*bv.w; \
    acc[1][0] += av.y*bv.x; acc[1][1] += av.y*bv.y; acc[1][2] += av.y*bv.z; acc[1][3] += av.y*bv.w; \
    acc[2][0] += av.z*bv.x; acc[2][1] += av.z*bv.y; acc[2][2] += av.z*bv.z; acc[2][3] += av.z*bv.w; \
    acc[3][0] += av.w*bv.x; acc[3][1] += av.w*bv.y; acc[3][2] += av.w*bv.z; acc[3][3] += av.w*bv.w;

// ---------------- GEMM1: h1 = x @ W1 (64x64 tile, 4x4/thread) ----------------
__global__ __launch_bounds__(256) void gemm1_kernel(
    const float* __restrict__ X, const float* __restrict__ W,
    const float* __restrict__ a_s, const float* __restrict__ a_d,
    unsigned short* __restrict__ Hb, unsigned short* __restrict__ as1b,
    float* __restrict__ adn, int N)
{
    __shared__ float At[128 * 64];
    __shared__ float Bs[128 * 64];
    const int tid = threadIdx.x;
    const int r_base = blockIdx.x * 64;
    {
        const float4* W4 = (const float4*)W;
        float4* B4 = (float4*)Bs;
#pragma unroll
        for (int it = 0; it < 8; ++it) B4[tid + it * 256] = W4[tid + it * 256];
    }
    {
        const float4* X4 = (const float4*)X;
#pragma unroll
        for (int it = 0; it < 2; ++it) {
            int t = tid + it * 256;
            int rg = t & 15, cg = t >> 4;
            float4 rw[4];
#pragma unroll
            for (int j = 0; j < 4; ++j) {
                int r = r_base + rg * 4 + j;
                rw[j] = (r < N) ? X4[(size_t)r * 32 + cg] : make_float4(0.f, 0.f, 0.f, 0.f);
            }
            int rsw = 4 * (rg ^ (cg & 15));
            int k0 = cg * 4;
            *(float4*)&At[(k0    ) * 64 + rsw] = make_float4(rw[0].x, rw[1].x, rw[2].x, rw[3].x);
            *(float4*)&At[(k0 + 1) * 64 + rsw] = make_float4(rw[0].y, rw[1].y, rw[2].y, rw[3].y);
            *(float4*)&At[(k0 + 2) * 64 + rsw] = make_float4(rw[0].z, rw[1].z, rw[2].z, rw[3].z);
            *(float4*)&At[(k0 + 3) * 64 + rsw] = make_float4(rw[0].w, rw[1].w, rw[2].w, rw[3].w);
        }
    }
    __syncthreads();
    const int m  = tid & 15;
    const int ci = (tid >> 4) * 4;
    float acc[4][4] = {};
#pragma unroll 4
    for (int kq = 0; kq < 32; ++kq) {
        int aoff = kq * 256 + 4 * (m ^ (kq & 15));
        int boff = kq * 256 + ci;
        float4 a0 = *(const float4*)&At[aoff];
        float4 a1 = *(const float4*)&At[aoff + 64];
        float4 a2 = *(const float4*)&At[aoff + 128];
        float4 a3 = *(const float4*)&At[aoff + 192];
        float4 b0 = *(const float4*)&Bs[boff];
        float4 b1 = *(const float4*)&Bs[boff + 64];
        float4 b2 = *(const float4*)&Bs[boff + 128];
        float4 b3 = *(const float4*)&Bs[boff + 192];
        MAC16(a0, b0); MAC16(a1, b1); MAC16(a2, b2); MAC16(a3, b3);
    }
    float asv[4] = {a_s[ci], a_s[ci + 1], a_s[ci + 2], a_s[ci + 3]};
    float adv[4] = {a_d[ci], a_d[ci + 1], a_d[ci + 2], a_d[ci + 3]};
    int head = ci >> 3;
    bool owner = ((tid >> 4) & 1) == 0;
#pragma unroll
    for (int j = 0; j < 4; ++j) {
        int r = r_base + m * 4 + j;
        if (r < N) {
            ushort4 pk;
            pk.x = f2b(acc[j][0]); pk.y = f2b(acc[j][1]);
            pk.z = f2b(acc[j][2]); pk.w = f2b(acc[j][3]);
            *(ushort4*)&Hb[(size_t)r * 64 + ci] = pk;
        }
        float ps = acc[j][0]*asv[0] + acc[j][1]*asv[1] + acc[j][2]*asv[2] + acc[j][3]*asv[3];
        float pd = acc[j][0]*adv[0] + acc[j][1]*adv[1] + acc[j][2]*adv[2] + acc[j][3]*adv[3];
        ps += __shfl_xor(ps, 16);
        pd += __shfl_xor(pd, 16);
        if (owner && r < N) { as1b[r * 8 + head] = f2b(ps); adn[r * 8 + head] = pd; }
    }
}

// ---------------- GEMM2: z = h2 @ W2 (64x64 tile) ----------------
__global__ __launch_bounds__(256) void gemm2_kernel(
    const float* __restrict__ X, const float* __restrict__ W,
    const float* __restrict__ a_s, const float* __restrict__ a_d,
    unsigned short* __restrict__ Zb, unsigned short* __restrict__ as2b,
    float* __restrict__ adn, int N)
{
    __shared__ float At[64 * 64];
    __shared__ float Bs[64 * 64];
    __shared__ float Ps[4][16][4], Pd[4][16][4];
    const int tid = threadIdx.x;
    const int r_base = blockIdx.x * 64;
    {
        const float4* W4 = (const float4*)W;
        float4* B4 = (float4*)Bs;
#pragma unroll
        for (int it = 0; it < 4; ++it) B4[tid + it * 256] = W4[tid + it * 256];
    }
    {
        const float4* X4 = (const float4*)X;
        int rg = tid & 15, cg = tid >> 4;
        float4 rw[4];
#pragma unroll
        for (int j = 0; j < 4; ++j) {
            int r = r_base + rg * 4 + j;
            rw[j] = (r < N) ? X4[(size_t)r * 16 + cg] : make_float4(0.f, 0.f, 0.f, 0.f);
        }
        int rsw = 4 * (rg ^ (cg & 15));
        int k0 = cg * 4;
        *(float4*)&At[(k0    ) * 64 + rsw] = make_float4(rw[0].x, rw[1].x, rw[2].x, rw[3].x);
        *(float4*)&At[(k0 + 1) * 64 + rsw] = make_float4(rw[0].y, rw[1].y, rw[2].y, rw[3].y);
        *(float4*)&At[(k0 + 2) * 64 + rsw] = make_float4(rw[0].z, rw[1].z, rw[2].z, rw[3].z);
        *(float4*)&At[(k0 + 3) * 64 + rsw] = make_float4(rw[0].w, rw[1].w, rw[2].w, rw[3].w);
    }
    __syncthreads();
    const int m  = tid & 15;
    const int ci = (tid >> 4) * 4;
    float acc[4][4] = {};
#pragma unroll 4
    for (int kq = 0; kq < 16; ++kq) {
        int aoff = kq * 256 + 4 * (m ^ (kq & 15));
        int boff = kq * 256 + ci;
        float4 a0 = *(const float4*)&At[aoff];
        float4 a1 = *(const float4*)&At[aoff + 64];
        float4 a2 = *(const float4*)&At[aoff + 128];
        float4 a3 = *(const float4*)&At[aoff + 192];
        float4 b0 = *(const float4*)&Bs[boff];
        float4 b1 = *(const float4*)&Bs[boff + 64];
        float4 b2 = *(const float4*)&Bs[boff + 128];
        float4 b3 = *(const float4*)&Bs[boff + 192];
        MAC16(a0, b0); MAC16(a1, b1); MAC16(a2, b2); MAC16(a3, b3);
    }
    float asv[4] = {a_s[ci], a_s[ci + 1], a_s[ci + 2], a_s[ci + 3]};
    float adv[4] = {a_d[ci], a_d[ci + 1], a_d[ci + 2], a_d[ci + 3]};
    int w = tid >> 6;
    float ps[4], pd[4];
#pragma unroll
    for (int j = 0; j < 4; ++j) {
        int r = r_base + m * 4 + j;
        if (r < N) {
            ushort4 pk;
            pk.x = f2b(acc[j][0]); pk.y = f2b(acc[j][1]);
            pk.z = f2b(acc[j][2]); pk.w = f2b(acc[j][3]);
            *(ushort4*)&Zb[(size_t)r * 64 + ci] = pk;
        }
        ps[j] = acc[j][0]*asv[0] + acc[j][1]*asv[1] + acc[j][2]*asv[2] + acc[j][3]*asv[3];
        pd[j] = acc[j][0]*adv[0] + acc[j][1]*adv[1] + acc[j][2]*adv[2] + acc[j][3]*adv[3];
        ps[j] += __shfl_xor(ps[j], 16); ps[j] += __shfl_xor(ps[j], 32);
        pd[j] += __shfl_xor(pd[j], 16); pd[j] += __shfl_xor(pd[j], 32);
    }
    if (((tid >> 4) & 3) == 0) {
#pragma unroll
        for (int j = 0; j < 4; ++j) { Ps[w][m][j] = ps[j]; Pd[w][m][j] = pd[j]; }
    }
    __syncthreads();
    if (tid < 64) {
        int r = r_base + tid;
        if (r < N) {
            int mm = tid >> 2, jj = tid & 3;
            as2b[r] = f2b(Ps[0][mm][jj] + Ps[1][mm][jj] + Ps[2][mm][jj] + Ps[3][mm][jj]);
            adn[r]  = Pd[0][mm][jj] + Pd[1][mm][jj] + Pd[2][mm][jj] + Pd[3][mm][jj];
        }
    }
}

// ================= Tile-stable bucketed CSR build (proven replay-safe) =================
__global__ __launch_bounds__(256) void bhist_kernel(
    const int* __restrict__ dst, int E, int T, int shift, int NB, int NT,
    int* __restrict__ thist)
{
    __shared__ int h[256];
    int t = blockIdx.x, tid = threadIdx.x;
    for (int i = tid; i < NB; i += 256) h[i] = 0;
    __syncthreads();
    int e0 = t * T, e1 = min(E, e0 + T);
    for (int e = e0 + tid; e < e1; e += 256) atomicAdd(&h[dst[e] >> shift], 1);
    __syncthreads();
    for (int i = tid; i < NB; i += 256) thist[(size_t)i * NT + t] = h[i];
}

__global__ __launch_bounds__(256) void btot_kernel(
    const int* __restrict__ thist, int NT, int* __restrict__ btot)
{
    int b = blockIdx.x, tid = threadIdx.x;
    __shared__ int wsum[4];
    int s = 0;
    for (int t = tid; t < NT; t += 256) s += thist[(size_t)b * NT + t];
#pragma unroll
    for (int d = 1; d < 64; d <<= 1) s += __shfl_xor(s, d);
    if ((tid & 63) == 0) wsum[tid >> 6] = s;
    __syncthreads();
    if (tid == 0) btot[b] = wsum[0] + wsum[1] + wsum[2] + wsum[3];
}

__global__ __launch_bounds__(64) void bbase_kernel(
    const int* __restrict__ btot, int NB, int* __restrict__ bbase)
{
    int lane = threadIdx.x;
    int carry = 0;
    for (int base = 0; base < NB; base += 64) {
        int i = base + lane;
        int v = (i < NB) ? btot[i] : 0;
        int incl = v;
#pragma unroll
        for (int d = 1; d < 64; d <<= 1) {
            int t = __shfl_up(incl, d);
            if (lane >= d) incl += t;
        }
        if (i < NB) bbase[i] = carry + incl - v;
        carry += __shfl(incl, 63);
    }
    if (lane == 0) bbase[NB] = carry;
}

__global__ __launch_bounds__(256) void bofs_kernel(
    int* __restrict__ thist, int NT, const int* __restrict__ bbase)
{
    int b = blockIdx.x, tid = threadIdx.x;
    int lane = tid & 63, w = tid >> 6;
    __shared__ int wsum[4];
    __shared__ int carry_s;
    if (tid == 0) carry_s = bbase[b];
    __syncthreads();
    for (int base = 0; base < NT; base += 256) {
        int t = base + tid;
        int v = (t < NT) ? thist[(size_t)b * NT + t] : 0;
        int incl = v;
#pragma unroll
        for (int d = 1; d < 64; d <<= 1) {
            int x = __shfl_up(incl, d);
            if (lane >= d) incl += x;
        }
        if (lane == 63) wsum[w] = incl;
        __syncthreads();
        int woff = 0;
        for (int i = 0; i < w; ++i) woff += wsum[i];
        if (t < NT) thist[(size_t)b * NT + t] = carry_s + woff + incl - v;
        __syncthreads();
        if (tid == 0) carry_s += wsum[0] + wsum[1] + wsum[2] + wsum[3];
        __syncthreads();
    }
}

__global__ __launch_bounds__(256) void bscatter_kernel(
    const int* __restrict__ src, const int* __restrict__ dst, int E, int T,
    int shift, int NB, int NT, const int* __restrict__ thist, int2* __restrict__ stg)
{
    __shared__ int cur[256];
    int t = blockIdx.x, tid = threadIdx.x;
    for (int i = tid; i < NB; i += 256) cur[i] = thist[(size_t)i * NT + t];
    __syncthreads();
    int e0 = t * T, e1 = min(E, e0 + T);
    for (int e = e0 + tid; e < e1; e += 256) {
        int d = dst[e];
        int pos = atomicAdd(&cur[d >> shift], 1);
        stg[pos] = make_int2(src[e], d);
    }
}

__global__ __launch_bounds__(256) void bbuild_kernel(
    const int2* __restrict__ stg, const int* __restrict__ bbase, int shift, int N,
    int* __restrict__ offv, int* __restrict__ cnt, int* __restrict__ csr)
{
    __shared__ int lcnt[1024], loff[1024], lfill[1024];
    int b = blockIdx.x, tid = threadIdx.x;
    int bs = 1 << shift;
    int n0 = b << shift;
    int e0 = bbase[b], e1 = bbase[b + 1];
    for (int i = tid; i < bs; i += 256) lcnt[i] = 0;
    __syncthreads();
    for (int e = e0 + tid; e < e1; e += 256) atomicAdd(&lcnt[stg[e].y - n0], 1);
    __syncthreads();
    if (tid < 64) {
        int seg = bs >> 6;
        int j0 = tid * seg;
        int local = 0;
        for (int j = 0; j < seg; ++j) {
            int n = n0 + j0 + j;
            local += (n < N) ? lcnt[j0 + j] + 1 : 0;
        }
        int incl = local;
#pragma unroll
        for (int d = 1; d < 64; d <<= 1) {
            int t2 = __shfl_up(incl, d);
            if (tid >= d) incl += t2;
        }
        int run = incl - local;
        for (int j = 0; j < seg; ++j) {
            int n = n0 + j0 + j;
            int v = (n < N) ? lcnt[j0 + j] + 1 : 0;
            loff[j0 + j] = run;
            run += v;
        }
    }
    __syncthreads();
    int csr_base = e0 + n0;
    for (int i = tid; i < bs; i += 256) {
        int n = n0 + i;
        if (n < N) {
            int o = csr_base + loff[i];
            offv[n] = o;
            cnt[n] = lcnt[i];
            csr[o] = n;          // self loop at slot 0
            lfill[i] = loff[i] + 1;
        }
    }
    __syncthreads();
    for (int e = e0 + tid; e < e1; e += 256) {
        int2 p = stg[e];
        int pos = atomicAdd(&lfill[p.y - n0], 1);
        csr[csr_base + pos] = p.x;
    }
}

// ---------------- GAT layer 1: 4-edge-wide bf16 gather (8B/lane), distributed p ----------------
__global__ __launch_bounds__(256) void gat1_kernel(
    const unsigned short* __restrict__ Hb, const unsigned short* __restrict__ as1b,
    const float* __restrict__ adn, const float* __restrict__ b1,
    const int* __restrict__ offv, const int* __restrict__ cnt,
    const int* __restrict__ csr, float* __restrict__ h2, int N)
{
    int n = blockIdx.x * 4 + (threadIdx.x >> 6);
    if (n >= N) return;
    int lane = threadIdx.x & 63;
    int base = offv[n];
    int deg = cnt[n] + 1;

    if (deg <= 64) {
        int cg   = lane >> 4;            // edge subgroup 0..3
        int ch4  = (lane & 15) * 4;      // 4-channel group
        int headA = (lane & 15) >> 1;    // head owning ch4..ch4+3
        int jC = lane >> 3, hC = lane & 7;  // p-compute layout (edge-slot, head)
        float adC = adn[n * 8 + hC];
        int sreg = csr[base + (lane < deg ? lane : 0)];
        float a0 = 0.f, a1 = 0.f, a2 = 0.f, a3 = 0.f, psum = 0.f;
        int nch = (deg + 7) >> 3;
        for (int c = 0; c < nch; ++c) {
            int c0 = c * 8;
            int idxC = c0 + jC;
            int sj = __shfl(sreg, idxC);
            float p = (idxC < deg) ? __expf(lrelu(b2f(as1b[sj * 8 + hC]) + adC)) : 0.f;
#pragma unroll
            for (int sub = 0; sub < 2; ++sub) {
                int el = sub * 4 + cg;               // 0..7
                int s  = __shfl(sreg, c0 + el);      // <= 63 index
                float pj = __shfl(p, el * 8 + headA);
                uint2 d = *(const uint2*)(Hb + (size_t)s * 64 + ch4);
                a0 += pj * __uint_as_float(d.x << 16);
                a1 += pj * __uint_as_float(d.x & 0xffff0000u);
                a2 += pj * __uint_as_float(d.y << 16);
                a3 += pj * __uint_as_float(d.y & 0xffff0000u);
                psum += pj;
            }
        }
        a0 += __shfl_xor(a0, 16); a0 += __shfl_xor(a0, 32);
        a1 += __shfl_xor(a1, 16); a1 += __shfl_xor(a1, 32);
        a2 += __shfl_xor(a2, 16); a2 += __shfl_xor(a2, 32);
        a3 += __shfl_xor(a3, 16); a3 += __shfl_xor(a3, 32);
        psum += __shfl_xor(psum, 16); psum += __shfl_xor(psum, 32);
        if (lane < 16) {
            float rp = 1.f / psum;
            float4 bb = *(const float4*)&b1[ch4];
            float v0 = a0 * rp + bb.x, v1 = a1 * rp + bb.y,
                  v2 = a2 * rp + bb.z, v3 = a3 * rp + bb.w;
            v0 = v0 > 0.f ? v0 : __expf(v0) - 1.f;
            v1 = v1 > 0.f ? v1 : __expf(v1) - 1.f;
            v2 = v2 > 0.f ? v2 : __expf(v2) - 1.f;
            v3 = v3 > 0.f ? v3 : __expf(v3) - 1.f;
            *(float4*)&h2[(size_t)n * 64 + ch4] = make_float4(v0, v1, v2, v3);
        }
    } else {
        // fallback (deg > 64): per-lane-channel layout
        int hh = lane >> 3;
        float ad = adn[n * 8 + hh];
        float acc = 0.f, psum = 0.f;
        for (int k = 0; k < deg; ++k) {
            int s = __builtin_amdgcn_readfirstlane(csr[base + k]);
            float p = __expf(lrelu(b2f(as1b[s * 8 + hh]) + ad));
            acc += p * b2f(Hb[(size_t)s * 64 + lane]);
            psum += p;
        }
        float v = acc / psum + b1[lane];
        h2[(size_t)n * 64 + lane] = v > 0.f ? v : __expf(v) - 1.f;
    }
}

// ---------------- GAT layer 2: 4-edge-wide bf16 gather, 1 head ----------------
__global__ __launch_bounds__(256) void gat2_kernel(
    const unsigned short* __restrict__ Zb, const unsigned short* __restrict__ as2b,
    const float* __restrict__ adn, const float* __restrict__ b2,
    const int* __restrict__ offv, const int* __restrict__ cnt,
    const int* __restrict__ csr, float* __restrict__ out, int N)
{
    int n = blockIdx.x * 4 + (threadIdx.x >> 6);
    if (n >= N) return;
    int lane = threadIdx.x & 63;
    int base = offv[n];
    int deg = cnt[n] + 1;
    float ad = adn[n];

    if (deg <= 64) {
        int cg  = lane >> 4;
        int ch4 = (lane & 15) * 4;
        int sreg = csr[base + (lane < deg ? lane : 0)];
        float p = (lane < deg) ? __expf(lrelu(b2f(as2b[sreg]) + ad)) : 0.f;
        float psum = p;
#pragma unroll
        for (int d = 1; d < 64; d <<= 1) psum += __shfl_xor(psum, d);
        float a0 = 0.f, a1 = 0.f, a2 = 0.f, a3 = 0.f;
        int nkk = (deg + 3) >> 2;
        for (int kk = 0; kk < nkk; ++kk) {
            int idx = kk * 4 + cg;               // <= 63
            int s = __shfl(sreg, idx);
            float pj = __shfl(p, idx);           // 0 beyond deg
            uint2 d = *(const uint2*)(Zb + (size_t)s * 64 + ch4);
            a0 += pj * __uint_as_float(d.x << 16);
            a1 += pj * __uint_as_float(d.x & 0xffff0000u);
            a2 += pj * __uint_as_float(d.y << 16);
            a3 += pj * __uint_as_float(d.y & 0xffff0000u);
        }
        a0 += __shfl_xor(a0, 16); a0 += __shfl_xor(a0, 32);
        a1 += __shfl_xor(a1, 16); a1 += __shfl_xor(a1, 32);
        a2 += __shfl_xor(a2, 16); a2 += __shfl_xor(a2, 32);
        a3 += __shfl_xor(a3, 16); a3 += __shfl_xor(a3, 32);
        if (lane < 16) {
            float rp = 1.f / psum;
            float4 bb = *(const float4*)&b2[ch4];
            *(float4*)&out[(size_t)n * 64 + ch4] =
                make_float4(a0 * rp + bb.x, a1 * rp + bb.y, a2 * rp + bb.z, a3 * rp + bb.w);
        }
    } else {
        float acc = 0.f, psum = 0.f;
        for (int k = 0; k < deg; ++k) {
            int s = __builtin_amdgcn_readfirstlane(csr[base + k]);
            float p = __expf(lrelu(b2f(as2b[s]) + ad));
            acc += p * b2f(Zb[(size_t)s * 64 + lane]);
            psum += p;
        }
        out[(size_t)n * 64 + lane] = acc / psum + b2[lane];
    }
}

// ---------------- decode: 4 queries/wave, float4 loads ----------------
__global__ __launch_bounds__(256) void decode_kernel(
    const float* __restrict__ z2, const int* __restrict__ q, int Q, float* __restrict__ out)
{
    int w = blockIdx.x * 4 + (threadIdx.x >> 6);
    int lane = threadIdx.x & 63;
    int cg = lane >> 4, ch4 = (lane & 15) * 4;
    int i = w * 4 + cg;
    int ic = min(i, Q - 1);
    int a = q[ic], b = q[Q + ic];
    float4 va = *(const float4*)&z2[(size_t)a * 64 + ch4];
    float4 vb = *(const float4*)&z2[(size_t)b * 64 + ch4];
    float v = va.x * vb.x + va.y * vb.y + va.z * vb.z + va.w * vb.w;
    v += __shfl_xor(v, 1); v += __shfl_xor(v, 2);
    v += __shfl_xor(v, 4); v += __shfl_xor(v, 8);
    if ((lane & 15) == 0 && i < Q) out[i] = 1.f / (1.f + __expf(-v));
}

extern "C" void kernel_launch(void* const* d_in, const int* in_sizes, int n_in,
                              void* d_out, int out_size, void* d_ws, size_t ws_size,
                              hipStream_t stream)
{
    const float* x   = (const float*)d_in[0];
    const int*   ei  = (const int*)d_in[1];
    const int*   qe  = (const int*)d_in[2];
    const float* W1  = (const float*)d_in[3];
    const float* as1 = (const float*)d_in[4];
    const float* ad1 = (const float*)d_in[5];
    const float* b1  = (const float*)d_in[6];
    const float* W2  = (const float*)d_in[7];
    const float* as2 = (const float*)d_in[8];
    const float* ad2 = (const float*)d_in[9];
    const float* b2  = (const float*)d_in[10];

    const int N = in_sizes[0] / 128;
    const int E = in_sizes[1] / 2;
    const int Q = in_sizes[2] / 2;

    float* out = (float*)d_out;

    int shift = 9;
    while ((((N + (1 << shift) - 1) >> shift)) > 256 && shift < 10) shift++;
    const int NB = (N + (1 << shift) - 1) >> shift;
    const int T  = 4096;
    const int NT = (E + T - 1) / T;

    char* ws = (char*)d_ws;
    size_t o = 0;
    auto alloc = [&](size_t bytes) -> void* {
        void* p = ws + o;
        o += (bytes + 255) & ~(size_t)255;
        return p;
    };
    unsigned short* hb   = (unsigned short*)alloc((size_t)N * 64 * 2); // h1 bf16, later z bf16
    float* f32buf        = (float*)alloc((size_t)N * 64 * 4);          // h2 f32, later z2 f32
    unsigned short* as1b = (unsigned short*)alloc((size_t)N * 8 * 2);
    float* adn1          = (float*)alloc((size_t)N * 8 * 4);
    unsigned short* as2b = (unsigned short*)alloc((size_t)N * 2);
    float* adn2          = (float*)alloc((size_t)N * 4);
    int*   cnt    = (int*)alloc((size_t)N * 4);
    int*   offv   = (int*)alloc((size_t)N * 4);
    int*   csr    = (int*)alloc((size_t)(E + N) * 4);
    int*   thist  = (int*)alloc((size_t)NB * NT * 4);   // bucket-major [b][t]
    int*   btot   = (int*)alloc((size_t)NB * 4);
    int*   bbase  = (int*)alloc((size_t)(NB + 1) * 4);
    int2*  stg    = (int2*)alloc((size_t)E * 8);

    const int* esrc = ei;
    const int* edst = ei + E;

    int nodeBlocks4 = (N + 3) / 4;
    int tileBlocks  = (N + 63) / 64;

    gemm1_kernel<<<tileBlocks, 256, 0, stream>>>(x, W1, as1, ad1, hb, as1b, adn1, N);
    bhist_kernel<<<NT, 256, 0, stream>>>(edst, E, T, shift, NB, NT, thist);
    btot_kernel<<<NB, 256, 0, stream>>>(thist, NT, btot);
    bbase_kernel<<<1, 64, 0, stream>>>(btot, NB, bbase);
    bofs_kernel<<<NB, 256, 0, stream>>>(thist, NT, bbase);
    bscatter_kernel<<<NT, 256, 0, stream>>>(esrc, edst, E, T, shift, NB, NT, thist, stg);
    bbuild_kernel<<<NB, 256, 0, stream>>>(stg, bbase, shift, N, offv, cnt, csr);
    gat1_kernel<<<nodeBlocks4, 256, 0, stream>>>(hb, as1b, adn1, b1, offv, cnt, csr, f32buf, N);
    gemm2_kernel<<<tileBlocks, 256, 0, stream>>>(f32buf, W2, as2, ad2, hb, as2b, adn2, N);
    gat2_kernel<<<nodeBlocks4, 256, 0, stream>>>(hb, as2b, adn2, b2, offv, cnt, csr, f32buf, N);
    decode_kernel<<<(Q + 15) / 16, 256, 0, stream>>>(f32buf, qe, Q, out);
}